// Round 1
// baseline (560.218 us; speedup 1.0000x reference)
//
#include <hip/hip_runtime.h>
#include <math.h>

#define G_DIM    512
#define M2_DIM   64
#define N_LAYERS 16
#define N_SQ     9          // 9 squarings -> A^512; Frobenius -> trace(A^1024)
#define EPS_F    1e-20f

// ws layout: raw res_final per (b,s): ws[bs*512 + g], 72*512 floats total.

__global__ __launch_bounds__(512) void ista_main_kernel(
    const float* __restrict__ Dre, const float* __restrict__ Dim,
    const float* __restrict__ Cre, const float* __restrict__ Cim,
    float* __restrict__ out, float* __restrict__ ws)
{
    const int bs  = blockIdx.x;     // 0..71  (b*9+s)
    const int tid = threadIdx.x;    // 0..511
    const float* dre = Dre + (size_t)bs * (M2_DIM * G_DIM);
    const float* dim = Dim + (size_t)bs * (M2_DIM * G_DIM);

    // LDS: 8320 + 4224 + 128 + 512 + 128 + 16 + 8 floats = ~53.3 KB
    __shared__ __align__(16) float sB[64 * 130];    // 64x65 complex interleaved (pitch 130 floats)
    __shared__ __align__(16) float sTile[64 * 66];  // Gram staging: 64 rows x 32 complex (+pad)
    __shared__ __align__(16) float s_r[128];        // r vector, 64 complex
    __shared__ __align__(16) float s_res[512];      // current real iterate
    __shared__ __align__(16) float s_u[128];        // u = D*res, 64 complex
    __shared__ float s_red[16];
    __shared__ float s_scal[8]; // 0=gamma 1=theta 2=max|Dhr| 3=E(log scale) 4=tmp inv 5=lo 6=hi 7=norm2

    // ---------------- Phase A: r = vec(C^T) ----------------
    if (tid < 64) {
        int i = tid >> 3, j = tid & 7;              // m2 = i*8+j  ->  C[j][i]
        s_r[2 * tid]     = Cre[bs * 64 + j * 8 + i];
        s_r[2 * tid + 1] = Cim[bs * 64 + j * 8 + i];
    }
    __syncthreads();

    // ---------------- Phase B: Dhr[g] = sum_m conj(D[m,g]) r[m] ----------------
    float dhr_re = 0.f, dhr_im = 0.f;
    {
        const int g = tid;
        #pragma unroll 8
        for (int m = 0; m < M2_DIM; ++m) {
            float ar = dre[m * G_DIM + g], ai = dim[m * G_DIM + g];
            float rr = s_r[2 * m], ri = s_r[2 * m + 1];
            dhr_re += ar * rr + ai * ri;
            dhr_im += ar * ri - ai * rr;
        }
    }
    // block reduce: sum(dhr_re^2) and max(|Dhr|)
    {
        float sv = dhr_re * dhr_re;
        float mv = sqrtf(dhr_re * dhr_re + dhr_im * dhr_im);
        for (int off = 32; off; off >>= 1) {
            sv += __shfl_down(sv, off, 64);
            mv = fmaxf(mv, __shfl_down(mv, off, 64));
        }
        if ((tid & 63) == 0) { s_red[tid >> 6] = sv; s_red[8 + (tid >> 6)] = mv; }
        __syncthreads();
        if (tid == 0) {
            float ssum = 0.f, mmax = 0.f;
            for (int k = 0; k < 8; ++k) { ssum += s_red[k]; mmax = fmaxf(mmax, s_red[8 + k]); }
            s_scal[7] = ssum;   // ||Re(Dhr)||^2
            s_scal[2] = mmax;   // max|Dhr|
        }
        __syncthreads();
    }
    float res_g = dhr_re / (sqrtf(s_scal[7]) + EPS_F);
    s_res[tid] = res_g;
    // (visibility guaranteed by the many barriers before first use)

    // ---------------- Phase C: Gram A = D * D^H  (64x64 complex) ----------------
    const int ti = tid >> 4;         // 0..31
    const int tj = tid & 15;         // 0..15
    const int i0 = 2 * ti, j0 = 4 * tj;
    float accR[2][4] = {{0.f}}, accI[2][4] = {{0.f}};
    for (int gc = 0; gc < G_DIM; gc += 32) {
        __syncthreads();  // previous chunk's readers done
        for (int e = tid; e < 2048; e += 512) {
            int row = e >> 5, col = e & 31;
            sTile[row * 66 + 2 * col]     = dre[row * G_DIM + gc + col];
            sTile[row * 66 + 2 * col + 1] = dim[row * G_DIM + gc + col];
        }
        __syncthreads();
        #pragma unroll 4
        for (int gg = 0; gg < 32; ++gg) {
            float2 a0 = *(float2*)&sTile[(i0    ) * 66 + 2 * gg];
            float2 a1 = *(float2*)&sTile[(i0 + 1) * 66 + 2 * gg];
            #pragma unroll
            for (int q = 0; q < 4; ++q) {
                float2 b = *(float2*)&sTile[(j0 + q) * 66 + 2 * gg];
                // A[i][j] += D[i,g] * conj(D[j,g])
                accR[0][q] += a0.x * b.x + a0.y * b.y;
                accI[0][q] += a0.y * b.x - a0.x * b.y;
                accR[1][q] += a1.x * b.x + a1.y * b.y;
                accI[1][q] += a1.y * b.x - a1.x * b.y;
            }
        }
    }
    __syncthreads();
    #pragma unroll
    for (int p = 0; p < 2; ++p)
        #pragma unroll
        for (int q = 0; q < 4; ++q) {
            sB[(i0 + p) * 130 + 2 * (j0 + q)]     = accR[p][q];
            sB[(i0 + p) * 130 + 2 * (j0 + q) + 1] = accI[p][q];
        }
    __syncthreads();

    // ---------------- Phase D: lambda_max via scaled repeated squaring ----------------
    // B_0 = A / s0, E_0 = log(s0);  B_{k+1} = B_k^2 / c_k, E_{k+1} = 2E_k + log(c_k)
    if (tid < 64) {
        float dv = sB[tid * 130 + 2 * tid];        // diag(A), real positive
        for (int off = 32; off; off >>= 1) dv = fmaxf(dv, __shfl_down(dv, off, 64));
        if (tid == 0) { s_scal[3] = logf(dv); s_scal[4] = 1.f / dv; }
    }
    __syncthreads();
    {
        float inv = s_scal[4];
        #pragma unroll
        for (int p = 0; p < 2; ++p)
            #pragma unroll
            for (int q = 0; q < 4; ++q) {
                sB[(i0 + p) * 130 + 2 * (j0 + q)]     *= inv;
                sB[(i0 + p) * 130 + 2 * (j0 + q) + 1] *= inv;
            }
    }
    __syncthreads();

    for (int sq = 0; sq < N_SQ; ++sq) {
        float bR[2][4] = {{0.f}}, bI[2][4] = {{0.f}};
        #pragma unroll 4
        for (int n = 0; n < 64; ++n) {
            float2 a0 = *(float2*)&sB[(i0    ) * 130 + 2 * n];
            float2 a1 = *(float2*)&sB[(i0 + 1) * 130 + 2 * n];
            #pragma unroll
            for (int q = 0; q < 4; ++q) {
                float2 b = *(float2*)&sB[n * 130 + 2 * (j0 + q)];
                bR[0][q] += a0.x * b.x - a0.y * b.y;
                bI[0][q] += a0.x * b.y + a0.y * b.x;
                bR[1][q] += a1.x * b.x - a1.y * b.y;
                bI[1][q] += a1.x * b.y + a1.y * b.x;
            }
        }
        // c = max |Re diag(B^2)|  (block reduce over owning threads)
        float dv = 0.f;
        #pragma unroll
        for (int p = 0; p < 2; ++p)
            #pragma unroll
            for (int q = 0; q < 4; ++q)
                if (i0 + p == j0 + q) dv = fmaxf(dv, fabsf(bR[p][q]));
        for (int off = 32; off; off >>= 1) dv = fmaxf(dv, __shfl_down(dv, off, 64));
        if ((tid & 63) == 0) s_red[tid >> 6] = dv;
        __syncthreads();   // also: all GEMM reads of sB complete
        if (tid == 0) {
            float m = 0.f;
            for (int k = 0; k < 8; ++k) m = fmaxf(m, s_red[k]);
            s_scal[3] = 2.f * s_scal[3] + logf(m);
            s_scal[4] = 1.f / m;
        }
        __syncthreads();
        float ic = s_scal[4];
        #pragma unroll
        for (int p = 0; p < 2; ++p)
            #pragma unroll
            for (int q = 0; q < 4; ++q) {
                sB[(i0 + p) * 130 + 2 * (j0 + q)]     = bR[p][q] * ic;
                sB[(i0 + p) * 130 + 2 * (j0 + q) + 1] = bI[p][q] * ic;
            }
        __syncthreads();
    }
    // Frobenius: trace(A^1024) = ||A^512||_F^2 = ||B_9||_F^2 * exp(2 E_9)
    {
        float fr = 0.f;
        #pragma unroll
        for (int p = 0; p < 2; ++p)
            #pragma unroll
            for (int q = 0; q < 4; ++q) {
                float x = sB[(i0 + p) * 130 + 2 * (j0 + q)];
                float y = sB[(i0 + p) * 130 + 2 * (j0 + q) + 1];
                fr += x * x + y * y;
            }
        for (int off = 32; off; off >>= 1) fr += __shfl_down(fr, off, 64);
        if ((tid & 63) == 0) s_red[tid >> 6] = fr;
        __syncthreads();
        if (tid == 0) {
            float fsum = 0.f;
            for (int k = 0; k < 8; ++k) fsum += s_red[k];
            float loglam = (2.f * s_scal[3] + logf(fsum)) * (1.f / 1024.f);
            float lmax = expf(loglam);
            float gamma = 1.f / lmax;
            s_scal[0] = gamma;
            s_scal[1] = 0.5f * s_scal[2] * gamma;   // theta = ALPHA * lam * gamma
        }
        __syncthreads();
    }

    // ---------------- Phase E: 16 ISTA layers ----------------
    const float gamma = s_scal[0];
    const float theta = s_scal[1];
    const int um = tid >> 3, uc = tid & 7;          // u-phase mapping
    float* out_init = out + 40960 + (size_t)bs * (N_LAYERS * G_DIM);

    for (int l = 0; l < N_LAYERS; ++l) {
        // u[m] = sum_g D[m,g] * res[g]   (complex * real)
        float ur = 0.f, ui = 0.f;
        #pragma unroll 8
        for (int i = 0; i < 64; ++i) {
            int g = uc * 64 + i;
            float rv = s_res[g];
            ur += dre[um * G_DIM + g] * rv;
            ui += dim[um * G_DIM + g] * rv;
        }
        for (int off = 4; off; off >>= 1) {
            ur += __shfl_down(ur, off, 8);
            ui += __shfl_down(ui, off, 8);
        }
        if (uc == 0) { s_u[2 * um] = ur; s_u[2 * um + 1] = ui; }
        __syncthreads();
        // w[g] = sum_m conj(D[m,g]) u[m];  s = res + gamma*(Dhr - w)
        float wr = 0.f, wi = 0.f;
        const int g = tid;
        #pragma unroll 8
        for (int m = 0; m < M2_DIM; ++m) {
            float ar = dre[m * G_DIM + g], ai = dim[m * G_DIM + g];
            float pr = s_u[2 * m], pi = s_u[2 * m + 1];
            wr += ar * pr + ai * pi;
            wi += ar * pi - ai * pr;
        }
        float sre = res_g + gamma * (dhr_re - wr);
        float sim = gamma * (dhr_im - wi);
        float mag = sqrtf(sre * sre + sim * sim);
        res_g = fmaxf(mag - theta, 0.f);
        out_init[l * G_DIM + g] = res_g;
        s_res[tid] = res_g;
        __syncthreads();
    }

    // ---------------- Phase F: epilogue (min-max norm + raw stash) ----------------
    {
        float mn = res_g, mx = res_g;
        for (int off = 32; off; off >>= 1) {
            mn = fminf(mn, __shfl_down(mn, off, 64));
            mx = fmaxf(mx, __shfl_down(mx, off, 64));
        }
        if ((tid & 63) == 0) { s_red[tid >> 6] = mn; s_red[8 + (tid >> 6)] = mx; }
        __syncthreads();
        if (tid == 0) {
            float a = s_red[0], b2 = s_red[8];
            for (int k = 1; k < 8; ++k) { a = fminf(a, s_red[k]); b2 = fmaxf(b2, s_red[8 + k]); }
            s_scal[5] = a; s_scal[6] = b2;
        }
        __syncthreads();
        out[bs * G_DIM + tid] = (res_g - s_scal[5]) / (s_scal[6] - s_scal[5] + EPS_F);
        ws[bs * G_DIM + tid] = res_g;
    }
}

__global__ __launch_bounds__(512) void ista_ave_kernel(
    const float* __restrict__ ws, float* __restrict__ out)
{
    const int b = blockIdx.x;    // 0..7
    const int g = threadIdx.x;   // 0..511
    __shared__ float s_red[16];
    __shared__ float s_scal[2];
    float acc = 0.f;
    #pragma unroll
    for (int s = 0; s < 9; ++s) acc += ws[(b * 9 + s) * G_DIM + g];
    acc *= (1.f / 9.f);
    float mn = acc, mx = acc;
    for (int off = 32; off; off >>= 1) {
        mn = fminf(mn, __shfl_down(mn, off, 64));
        mx = fmaxf(mx, __shfl_down(mx, off, 64));
    }
    if ((g & 63) == 0) { s_red[g >> 6] = mn; s_red[8 + (g >> 6)] = mx; }
    __syncthreads();
    if (g == 0) {
        float a = s_red[0], b2 = s_red[8];
        for (int k = 1; k < 8; ++k) { a = fminf(a, s_red[k]); b2 = fmaxf(b2, s_red[8 + k]); }
        s_scal[0] = a; s_scal[1] = b2;
    }
    __syncthreads();
    out[36864 + b * G_DIM + g] = (acc - s_scal[0]) / (s_scal[1] - s_scal[0] + EPS_F);
}

extern "C" void kernel_launch(void* const* d_in, const int* in_sizes, int n_in,
                              void* d_out, int out_size, void* d_ws, size_t ws_size,
                              hipStream_t stream) {
    const float* Dre = (const float*)d_in[0];
    const float* Dim = (const float*)d_in[1];
    const float* Cre = (const float*)d_in[2];
    const float* Cim = (const float*)d_in[3];
    float* out = (float*)d_out;
    float* ws  = (float*)d_ws;

    ista_main_kernel<<<72, 512, 0, stream>>>(Dre, Dim, Cre, Cim, out, ws);
    ista_ave_kernel<<<8, 512, 0, stream>>>(ws, out);
}

// Round 2
// 482.749 us; speedup vs baseline: 1.1605x; 1.1605x over previous
//
#include <hip/hip_runtime.h>
#include <math.h>

#define N_SQ   9          // 9 squarings -> A^512; Frobenius -> trace(A^1024)
#define EPS_F  1e-20f
#define PT     132        // sT pitch (floats): 64 complex + pad, 16B-aligned
#define PB     132        // sB pitch (floats)
#define PP     1032       // sP pitch (floats): 512 complex + pad, 16B-aligned

// ws: raw res_final per (b,s): ws[bs*512 + g], 72*512 floats.

__global__ __launch_bounds__(512, 2) void ista_main_kernel(
    const float* __restrict__ Dre, const float* __restrict__ Dim,
    const float* __restrict__ Cre, const float* __restrict__ Cim,
    float* __restrict__ out, float* __restrict__ ws)
{
    const int bs = blockIdx.x;     // 0..71
    const int t  = threadIdx.x;    // 0..511
    const int wv = t >> 6;         // wave 0..7
    const int ln = t & 63;         // lane
    const float* __restrict__ dre = Dre + (size_t)bs * 32768;
    const float* __restrict__ dim = Dim + (size_t)bs * 32768;

    // LDS: 8448 + 4224 + 512 + 128 + 16 + 8 floats = 53.3 KB
    __shared__ __align__(16) float sBuf[8448];   // sB (phases C/D) aliased as sP (phase E)
    __shared__ __align__(16) float sT[32 * PT];  // Gram staging, transposed [g][row]
    __shared__ __align__(16) float s_res[512];
    __shared__ __align__(16) float s_r[128];
    __shared__ float s_red[16];
    __shared__ float s_scal[8];  // 0=gamma 1=theta 2=max|Dhr| 3=E 4=1/c 5=lo 6=hi 7=norm2

    float* sB = sBuf;
    float* sP = sBuf;            // safe: barrier separates last sB read from first sP write

    // ---------------- Phase A: r = vec(C^T) ----------------
    if (t < 64) {
        int i = t >> 3, j = t & 7;
        s_r[2 * t]     = Cre[bs * 64 + j * 8 + i];
        s_r[2 * t + 1] = Cim[bs * 64 + j * 8 + i];
    }
    __syncthreads();

    // ---------------- Phase B: Dhr[g] = sum_m conj(D[m,g]) r[m]  (t = g, coalesced) ----------------
    float dhr_re = 0.f, dhr_im = 0.f;
    #pragma unroll 8
    for (int m = 0; m < 64; ++m) {
        float ar = dre[m * 512 + t], ai = dim[m * 512 + t];
        float rr = s_r[2 * m], ri = s_r[2 * m + 1];
        dhr_re += ar * rr + ai * ri;
        dhr_im += ar * ri - ai * rr;
    }
    {
        float sv = dhr_re * dhr_re;
        float mv = sqrtf(dhr_re * dhr_re + dhr_im * dhr_im);
        for (int off = 32; off; off >>= 1) {
            sv += __shfl_down(sv, off, 64);
            mv = fmaxf(mv, __shfl_down(mv, off, 64));
        }
        if (ln == 0) { s_red[wv] = sv; s_red[8 + wv] = mv; }
        __syncthreads();
        if (t == 0) {
            float ss = 0.f, mm = 0.f;
            for (int k = 0; k < 8; ++k) { ss += s_red[k]; mm = fmaxf(mm, s_red[8 + k]); }
            s_scal[7] = ss; s_scal[2] = mm; s_scal[3] = 0.f;  // E log-scale init
        }
        __syncthreads();
    }
    float res_g = dhr_re / (sqrtf(s_scal[7]) + EPS_F);
    s_res[t] = res_g;

    // ---------------- Phase C: Gram A = D * D^H (64x64), 4x4 tiles on 256 threads ----------------
    const bool cw = (t < 256);
    const int ti2 = (t >> 3) & 7, tj2 = t & 7;
    const int ti = (((t >> 6) >> 1) << 3) | ti2;   // wave-blocked: ti,tj in 0..15
    const int tj = (((t >> 6) & 1) << 3) | tj2;
    float accR[4][4] = {{0.f}}, accI[4][4] = {{0.f}};

    for (int gc = 0; gc < 512; gc += 32) {
        __syncthreads();   // protect sT from previous chunk's readers
        {
            int gl = t & 31, row0 = t >> 5;
            #pragma unroll
            for (int s = 0; s < 4; ++s) {
                int row = row0 + 16 * s;
                sT[gl * PT + 2 * row]     = dre[row * 512 + gc + gl];
                sT[gl * PT + 2 * row + 1] = dim[row * 512 + gc + gl];
            }
        }
        __syncthreads();
        if (cw) {
            #pragma unroll 4
            for (int gg = 0; gg < 32; ++gg) {
                const float* rp = &sT[gg * PT];
                float4 a0 = *(const float4*)(rp + 8 * ti);
                float4 a1 = *(const float4*)(rp + 8 * ti + 4);
                float4 b0 = *(const float4*)(rp + 8 * tj);
                float4 b1 = *(const float4*)(rp + 8 * tj + 4);
                float aR[4] = {a0.x, a0.z, a1.x, a1.z}, aI[4] = {a0.y, a0.w, a1.y, a1.w};
                float bR[4] = {b0.x, b0.z, b1.x, b1.z}, bI[4] = {b0.y, b0.w, b1.y, b1.w};
                #pragma unroll
                for (int p = 0; p < 4; ++p)
                    #pragma unroll
                    for (int q = 0; q < 4; ++q) {
                        // A[i][j] += D[i,g] * conj(D[j,g])
                        accR[p][q] += aR[p] * bR[q] + aI[p] * bI[q];
                        accI[p][q] += aI[p] * bR[q] - aR[p] * bI[q];
                    }
            }
        }
    }
    if (cw) {
        #pragma unroll
        for (int p = 0; p < 4; ++p) {
            *(float4*)&sB[(4 * ti + p) * PB + 8 * tj] =
                make_float4(accR[p][0], accI[p][0], accR[p][1], accI[p][1]);
            *(float4*)&sB[(4 * ti + p) * PB + 8 * tj + 4] =
                make_float4(accR[p][2], accI[p][2], accR[p][3], accI[p][3]);
        }
    }
    __syncthreads();

    // ---------------- Phase D: lambda_max via scaled squaring (Hermitian row-reads) ----------------
    for (int sq = 0; sq < N_SQ; ++sq) {
        float bRr[4][4] = {{0.f}}, bIr[4][4] = {{0.f}};
        if (cw) {
            #pragma unroll 2
            for (int n = 0; n < 64; ++n) {
                const float* rp = &sB[n * PB];
                float4 a0 = *(const float4*)(rp + 8 * ti);
                float4 a1 = *(const float4*)(rp + 8 * ti + 4);
                float4 b0 = *(const float4*)(rp + 8 * tj);
                float4 b1 = *(const float4*)(rp + 8 * tj + 4);
                float aR[4] = {a0.x, a0.z, a1.x, a1.z}, aI[4] = {a0.y, a0.w, a1.y, a1.w};
                float bR[4] = {b0.x, b0.z, b1.x, b1.z}, bI[4] = {b0.y, b0.w, b1.y, b1.w};
                #pragma unroll
                for (int p = 0; p < 4; ++p)
                    #pragma unroll
                    for (int q = 0; q < 4; ++q) {
                        // C[i][j] = sum_n conj(B[n][i]) * B[n][j]  (B Hermitian)
                        bRr[p][q] += aR[p] * bR[q] + aI[p] * bI[q];
                        bIr[p][q] += aR[p] * bI[q] - aI[p] * bR[q];
                    }
            }
        }
        // c = max Re diag
        float dv = 0.f;
        if (cw) {
            #pragma unroll
            for (int p = 0; p < 4; ++p)
                #pragma unroll
                for (int q = 0; q < 4; ++q)
                    if (4 * ti + p == 4 * tj + q) dv = fmaxf(dv, fabsf(bRr[p][q]));
        }
        for (int off = 32; off; off >>= 1) dv = fmaxf(dv, __shfl_down(dv, off, 64));
        if (ln == 0) s_red[wv] = dv;
        __syncthreads();   // also: all sB reads of this squaring complete
        if (t == 0) {
            float m = 0.f;
            for (int k = 0; k < 8; ++k) m = fmaxf(m, s_red[k]);
            s_scal[3] = 2.f * s_scal[3] + logf(m);
            s_scal[4] = 1.f / m;
        }
        __syncthreads();
        float ic = s_scal[4];
        if (sq < N_SQ - 1) {
            if (cw) {
                #pragma unroll
                for (int p = 0; p < 4; ++p) {
                    *(float4*)&sB[(4 * ti + p) * PB + 8 * tj] =
                        make_float4(bRr[p][0] * ic, bIr[p][0] * ic, bRr[p][1] * ic, bIr[p][1] * ic);
                    *(float4*)&sB[(4 * ti + p) * PB + 8 * tj + 4] =
                        make_float4(bRr[p][2] * ic, bIr[p][2] * ic, bRr[p][3] * ic, bIr[p][3] * ic);
                }
            }
            __syncthreads();
        } else {
            // Frobenius of scaled B_9 straight from registers
            float fr = 0.f;
            if (cw) {
                #pragma unroll
                for (int p = 0; p < 4; ++p)
                    #pragma unroll
                    for (int q = 0; q < 4; ++q)
                        fr += bRr[p][q] * bRr[p][q] + bIr[p][q] * bIr[p][q];
                fr *= ic * ic;
            }
            for (int off = 32; off; off >>= 1) fr += __shfl_down(fr, off, 64);
            if (ln == 0) s_red[wv] = fr;
            __syncthreads();
            if (t == 0) {
                float fsum = 0.f;
                for (int k = 0; k < 8; ++k) fsum += s_red[k];
                float loglam = (2.f * s_scal[3] + logf(fsum)) * (1.f / 1024.f);
                float gamma = expf(-loglam);
                s_scal[0] = gamma;
                s_scal[1] = 0.5f * s_scal[2] * gamma;
            }
            __syncthreads();
        }
    }

    // ---------------- Load D into registers: wave wv owns rows 8wv..8wv+7, lane owns g in [8ln,8ln+8) ----------------
    float dRr[8][8], dIr[8][8];
    #pragma unroll
    for (int k = 0; k < 8; ++k) {
        const float4* pr = (const float4*)&dre[(8 * wv + k) * 512 + 8 * ln];
        const float4* pi = (const float4*)&dim[(8 * wv + k) * 512 + 8 * ln];
        float4 x0 = pr[0], x1 = pr[1], y0 = pi[0], y1 = pi[1];
        dRr[k][0] = x0.x; dRr[k][1] = x0.y; dRr[k][2] = x0.z; dRr[k][3] = x0.w;
        dRr[k][4] = x1.x; dRr[k][5] = x1.y; dRr[k][6] = x1.z; dRr[k][7] = x1.w;
        dIr[k][0] = y0.x; dIr[k][1] = y0.y; dIr[k][2] = y0.z; dIr[k][3] = y0.w;
        dIr[k][4] = y1.x; dIr[k][5] = y1.y; dIr[k][6] = y1.z; dIr[k][7] = y1.w;
    }

    // ---------------- Phase E: 16 ISTA layers (register D, 2 barriers/layer) ----------------
    const float gamma = s_scal[0];
    const float theta = s_scal[1];
    float* out_init = out + 40960 + (size_t)bs * 8192;
    const bool b5 = (ln & 32) != 0, b4 = (ln & 16) != 0, b3 = (ln & 8) != 0;

    for (int l = 0; l < 16; ++l) {
        // u-partials: u[8wv+k] partial over lane's g-slice
        float4 q0 = *(const float4*)&s_res[8 * ln];
        float4 q1 = *(const float4*)&s_res[8 * ln + 4];
        float rs[8] = {q0.x, q0.y, q0.z, q0.w, q1.x, q1.y, q1.z, q1.w};
        float uR[8], uI[8];
        #pragma unroll
        for (int k = 0; k < 8; ++k) {
            float ar = 0.f, ai = 0.f;
            #pragma unroll
            for (int j = 0; j < 8; ++j) {
                ar += dRr[k][j] * rs[j];
                ai += dIr[k][j] * rs[j];
            }
            uR[k] = ar; uI[k] = ai;
        }
        // stream-splitting reduction: 8 sums over 64 lanes in 20 shfl
        float sR4[4], sI4[4];
        #pragma unroll
        for (int k = 0; k < 4; ++k) {
            float sendR = b5 ? uR[k] : uR[k + 4];
            float sendI = b5 ? uI[k] : uI[k + 4];
            float keepR = b5 ? uR[k + 4] : uR[k];
            float keepI = b5 ? uI[k + 4] : uI[k];
            sR4[k] = keepR + __shfl_xor(sendR, 32, 64);
            sI4[k] = keepI + __shfl_xor(sendI, 32, 64);
        }
        float tR2[2], tI2[2];
        #pragma unroll
        for (int k = 0; k < 2; ++k) {
            float sendR = b4 ? sR4[k] : sR4[k + 2];
            float sendI = b4 ? sI4[k] : sI4[k + 2];
            float keepR = b4 ? sR4[k + 2] : sR4[k];
            float keepI = b4 ? sI4[k + 2] : sI4[k];
            tR2[k] = keepR + __shfl_xor(sendR, 16, 64);
            tI2[k] = keepI + __shfl_xor(sendI, 16, 64);
        }
        float fR = (b3 ? tR2[1] : tR2[0]) + __shfl_xor(b3 ? tR2[0] : tR2[1], 8, 64);
        float fI = (b3 ? tI2[1] : tI2[0]) + __shfl_xor(b3 ? tI2[0] : tI2[1], 8, 64);
        fR += __shfl_xor(fR, 4, 64); fI += __shfl_xor(fI, 4, 64);
        fR += __shfl_xor(fR, 2, 64); fI += __shfl_xor(fI, 2, 64);
        fR += __shfl_xor(fR, 1, 64); fI += __shfl_xor(fI, 1, 64);
        // broadcast: lane 8m holds u[8wv+m]
        float ubR[8], ubI[8];
        #pragma unroll
        for (int m = 0; m < 8; ++m) {
            ubR[m] = __shfl(fR, 8 * m, 64);
            ubI[m] = __shfl(fI, 8 * m, 64);
        }
        // w-partials over own wave's rows, own g-slice
        float pwR[8], pwI[8];
        #pragma unroll
        for (int j = 0; j < 8; ++j) {
            float wr = 0.f, wi = 0.f;
            #pragma unroll
            for (int k = 0; k < 8; ++k) {
                wr += dRr[k][j] * ubR[k] + dIr[k][j] * ubI[k];
                wi += dRr[k][j] * ubI[k] - dIr[k][j] * ubR[k];
            }
            pwR[j] = wr; pwI[j] = wi;
        }
        {
            float* pp = &sP[wv * PP + 16 * ln];
            *(float4*)(pp)      = make_float4(pwR[0], pwI[0], pwR[1], pwI[1]);
            *(float4*)(pp + 4)  = make_float4(pwR[2], pwI[2], pwR[3], pwI[3]);
            *(float4*)(pp + 8)  = make_float4(pwR[4], pwI[4], pwR[5], pwI[5]);
            *(float4*)(pp + 12) = make_float4(pwR[6], pwI[6], pwR[7], pwI[7]);
        }
        __syncthreads();
        // final: t = g, sum 8 wave partials
        float wR = 0.f, wI = 0.f;
        #pragma unroll
        for (int w8 = 0; w8 < 8; ++w8) {
            float2 c = *(const float2*)&sP[w8 * PP + 2 * t];
            wR += c.x; wI += c.y;
        }
        float sre = res_g + gamma * (dhr_re - wR);
        float sim = gamma * (dhr_im - wI);
        float mag = sqrtf(sre * sre + sim * sim);
        res_g = fmaxf(mag - theta, 0.f);
        out_init[l * 512 + t] = res_g;
        s_res[t] = res_g;
        __syncthreads();
    }

    // ---------------- Phase F: epilogue ----------------
    {
        float mn = res_g, mx = res_g;
        for (int off = 32; off; off >>= 1) {
            mn = fminf(mn, __shfl_down(mn, off, 64));
            mx = fmaxf(mx, __shfl_down(mx, off, 64));
        }
        if (ln == 0) { s_red[wv] = mn; s_red[8 + wv] = mx; }
        __syncthreads();
        if (t == 0) {
            float a = s_red[0], b2 = s_red[8];
            for (int k = 1; k < 8; ++k) { a = fminf(a, s_red[k]); b2 = fmaxf(b2, s_red[8 + k]); }
            s_scal[5] = a; s_scal[6] = b2;
        }
        __syncthreads();
        out[bs * 512 + t] = (res_g - s_scal[5]) / (s_scal[6] - s_scal[5] + EPS_F);
        ws[bs * 512 + t] = res_g;
    }
}

__global__ __launch_bounds__(512) void ista_ave_kernel(
    const float* __restrict__ ws, float* __restrict__ out)
{
    const int b = blockIdx.x;    // 0..7
    const int g = threadIdx.x;   // 0..511
    __shared__ float s_red[16];
    __shared__ float s_scal[2];
    float acc = 0.f;
    #pragma unroll
    for (int s = 0; s < 9; ++s) acc += ws[(b * 9 + s) * 512 + g];
    acc *= (1.f / 9.f);
    float mn = acc, mx = acc;
    for (int off = 32; off; off >>= 1) {
        mn = fminf(mn, __shfl_down(mn, off, 64));
        mx = fmaxf(mx, __shfl_down(mx, off, 64));
    }
    if ((g & 63) == 0) { s_red[g >> 6] = mn; s_red[8 + (g >> 6)] = mx; }
    __syncthreads();
    if (g == 0) {
        float a = s_red[0], b2 = s_red[8];
        for (int k = 1; k < 8; ++k) { a = fminf(a, s_red[k]); b2 = fmaxf(b2, s_red[8 + k]); }
        s_scal[0] = a; s_scal[1] = b2;
    }
    __syncthreads();
    out[36864 + b * 512 + g] = (acc - s_scal[0]) / (s_scal[1] - s_scal[0] + EPS_F);
}

extern "C" void kernel_launch(void* const* d_in, const int* in_sizes, int n_in,
                              void* d_out, int out_size, void* d_ws, size_t ws_size,
                              hipStream_t stream) {
    const float* Dre = (const float*)d_in[0];
    const float* Dim = (const float*)d_in[1];
    const float* Cre = (const float*)d_in[2];
    const float* Cim = (const float*)d_in[3];
    float* out = (float*)d_out;
    float* ws  = (float*)d_ws;

    ista_main_kernel<<<72, 512, 0, stream>>>(Dre, Dim, Cre, Cim, out, ws);
    ista_ave_kernel<<<8, 512, 0, stream>>>(ws, out);
}

// Round 3
// 473.773 us; speedup vs baseline: 1.1825x; 1.0189x over previous
//
#include <hip/hip_runtime.h>
#include <math.h>

#define N_SQ   9          // 9 squarings -> A^512; Frobenius -> trace(A^1024)
#define EPS_F  1e-20f
#define PT     132        // sT pitch (floats): 64 complex + pad, 16B-aligned
#define PB     132        // sB pitch (floats)
#define PJ     1040       // sP per-j slab (floats): 8 waves * 130

// ws: raw res_final per (b,s): ws[bs*512 + g], 72*512 floats.

__global__ __launch_bounds__(512, 1) void ista_main_kernel(
    const float* __restrict__ Dre, const float* __restrict__ Dim,
    const float* __restrict__ Cre, const float* __restrict__ Cim,
    float* __restrict__ out, float* __restrict__ ws)
{
    const int bs = blockIdx.x;     // 0..71
    const int t  = threadIdx.x;    // 0..511
    const int wv = t >> 6;         // wave 0..7
    const int ln = t & 63;         // lane
    const float* __restrict__ dre = Dre + (size_t)bs * 32768;
    const float* __restrict__ dim = Dim + (size_t)bs * 32768;

    // LDS: 8448 + 4224 + 512 + 128 + 16 + 8 floats = 53.3 KB
    __shared__ __align__(16) float sBuf[8448];   // sB (phases C/D) aliased as sP (phase E)
    __shared__ __align__(16) float sT[32 * PT];  // Gram staging, transposed [g][row]
    __shared__ __align__(16) float s_res[512];
    __shared__ __align__(16) float s_r[128];
    __shared__ float s_red[16];
    __shared__ float s_scal[8];  // 0=gamma 1=theta 2=max|Dhr| 3=E 4=1/c 5=lo 6=hi 7=norm2

    float* sB = sBuf;
    float* sP = sBuf;            // safe: barrier separates last sB read from first sP write

    // ---------------- Phase A: r = vec(C^T) ----------------
    if (t < 64) {
        int i = t >> 3, j = t & 7;
        s_r[2 * t]     = Cre[bs * 64 + j * 8 + i];
        s_r[2 * t + 1] = Cim[bs * 64 + j * 8 + i];
    }
    __syncthreads();

    // ---------------- Phase B: Dhr[g] = sum_m conj(D[m,g]) r[m]  (t = g, coalesced) ----------------
    float dhr_re = 0.f, dhr_im = 0.f;
    #pragma unroll 8
    for (int m = 0; m < 64; ++m) {
        float ar = dre[m * 512 + t], ai = dim[m * 512 + t];
        float rr = s_r[2 * m], ri = s_r[2 * m + 1];
        dhr_re += ar * rr + ai * ri;
        dhr_im += ar * ri - ai * rr;
    }
    {
        float sv = dhr_re * dhr_re;
        float mv = sqrtf(dhr_re * dhr_re + dhr_im * dhr_im);
        for (int off = 32; off; off >>= 1) {
            sv += __shfl_down(sv, off, 64);
            mv = fmaxf(mv, __shfl_down(mv, off, 64));
        }
        if (ln == 0) { s_red[wv] = sv; s_red[8 + wv] = mv; }
        __syncthreads();
        if (t == 0) {
            float ss = 0.f, mm = 0.f;
            for (int k = 0; k < 8; ++k) { ss += s_red[k]; mm = fmaxf(mm, s_red[8 + k]); }
            s_scal[7] = ss; s_scal[2] = mm; s_scal[3] = 0.f;
        }
        __syncthreads();
    }
    float res_g = dhr_re / (sqrtf(s_scal[7]) + EPS_F);
    s_res[t] = res_g;

    // ---------------- Phase C: Gram A = D * D^H (64x64), 2x4 tiles on ALL 512 threads ----------------
    const int ti = t >> 4;        // 0..31 -> rows 2ti, 2ti+1
    const int tj = t & 15;        // 0..15 -> cols 4tj..4tj+3
    float accR[2][4] = {{0.f}}, accI[2][4] = {{0.f}};

    for (int gc = 0; gc < 512; gc += 32) {
        __syncthreads();   // protect sT from previous chunk's readers
        {
            int gl = t & 31, row0 = t >> 5;
            #pragma unroll
            for (int s = 0; s < 4; ++s) {
                int row = row0 + 16 * s;
                *(float2*)&sT[gl * PT + 2 * row] =
                    make_float2(dre[row * 512 + gc + gl], dim[row * 512 + gc + gl]);
            }
        }
        __syncthreads();
        #pragma unroll 4
        for (int gg = 0; gg < 32; ++gg) {
            const float* rp = &sT[gg * PT];
            float4 a  = *(const float4*)(rp + 4 * ti);
            float4 b0 = *(const float4*)(rp + 8 * tj);
            float4 b1 = *(const float4*)(rp + 8 * tj + 4);
            float aR[2] = {a.x, a.z}, aI[2] = {a.y, a.w};
            float bR[4] = {b0.x, b0.z, b1.x, b1.z}, bI[4] = {b0.y, b0.w, b1.y, b1.w};
            #pragma unroll
            for (int p = 0; p < 2; ++p)
                #pragma unroll
                for (int q = 0; q < 4; ++q) {
                    // A[i][j] += D[i,g] * conj(D[j,g])
                    accR[p][q] += aR[p] * bR[q] + aI[p] * bI[q];
                    accI[p][q] += aI[p] * bR[q] - aR[p] * bI[q];
                }
        }
    }
    #pragma unroll
    for (int p = 0; p < 2; ++p) {
        *(float4*)&sB[(2 * ti + p) * PB + 8 * tj] =
            make_float4(accR[p][0], accI[p][0], accR[p][1], accI[p][1]);
        *(float4*)&sB[(2 * ti + p) * PB + 8 * tj + 4] =
            make_float4(accR[p][2], accI[p][2], accR[p][3], accI[p][3]);
    }
    __syncthreads();

    // ---------------- Phase D: lambda_max via scaled squaring (Hermitian row-reads) ----------------
    // initial scale: max diag(A)
    if (t < 64) {
        float dv = sB[t * PB + 2 * t];
        for (int off = 32; off; off >>= 1) dv = fmaxf(dv, __shfl_down(dv, off, 64));
        if (t == 0) { s_scal[3] = logf(dv); s_scal[4] = 1.f / dv; }
    }
    __syncthreads();
    {
        float inv = s_scal[4];
        #pragma unroll
        for (int p = 0; p < 2; ++p)
            #pragma unroll
            for (int q = 0; q < 4; ++q) {
                sB[(2 * ti + p) * PB + 8 * tj + 2 * q]     *= inv;
                sB[(2 * ti + p) * PB + 8 * tj + 2 * q + 1] *= inv;
            }
    }
    __syncthreads();

    for (int sq = 0; sq < N_SQ; ++sq) {
        float bRr[2][4] = {{0.f}}, bIr[2][4] = {{0.f}};
        #pragma unroll 4
        for (int n = 0; n < 64; ++n) {
            const float* rp = &sB[n * PB];
            float4 a  = *(const float4*)(rp + 4 * ti);
            float4 b0 = *(const float4*)(rp + 8 * tj);
            float4 b1 = *(const float4*)(rp + 8 * tj + 4);
            float aR[2] = {a.x, a.z}, aI[2] = {a.y, a.w};
            float bR[4] = {b0.x, b0.z, b1.x, b1.z}, bI[4] = {b0.y, b0.w, b1.y, b1.w};
            #pragma unroll
            for (int p = 0; p < 2; ++p)
                #pragma unroll
                for (int q = 0; q < 4; ++q) {
                    // C[i][j] = sum_n conj(B[n][i]) * B[n][j]  (B Hermitian)
                    bRr[p][q] += aR[p] * bR[q] + aI[p] * bI[q];
                    bIr[p][q] += aR[p] * bI[q] - aI[p] * bR[q];
                }
        }
        // c = max |Re diag|
        float dv = 0.f;
        #pragma unroll
        for (int p = 0; p < 2; ++p)
            #pragma unroll
            for (int q = 0; q < 4; ++q)
                if (2 * ti + p == 4 * tj + q) dv = fmaxf(dv, fabsf(bRr[p][q]));
        for (int off = 32; off; off >>= 1) dv = fmaxf(dv, __shfl_down(dv, off, 64));
        if (ln == 0) s_red[wv] = dv;
        __syncthreads();   // also: all sB reads of this squaring complete
        if (t == 0) {
            float m = 0.f;
            for (int k = 0; k < 8; ++k) m = fmaxf(m, s_red[k]);
            s_scal[3] = 2.f * s_scal[3] + logf(m);
            s_scal[4] = 1.f / m;
        }
        __syncthreads();
        float ic = s_scal[4];
        if (sq < N_SQ - 1) {
            #pragma unroll
            for (int p = 0; p < 2; ++p) {
                *(float4*)&sB[(2 * ti + p) * PB + 8 * tj] =
                    make_float4(bRr[p][0] * ic, bIr[p][0] * ic, bRr[p][1] * ic, bIr[p][1] * ic);
                *(float4*)&sB[(2 * ti + p) * PB + 8 * tj + 4] =
                    make_float4(bRr[p][2] * ic, bIr[p][2] * ic, bRr[p][3] * ic, bIr[p][3] * ic);
            }
            __syncthreads();
        } else {
            float fr = 0.f;
            #pragma unroll
            for (int p = 0; p < 2; ++p)
                #pragma unroll
                for (int q = 0; q < 4; ++q)
                    fr += bRr[p][q] * bRr[p][q] + bIr[p][q] * bIr[p][q];
            fr *= ic * ic;
            for (int off = 32; off; off >>= 1) fr += __shfl_down(fr, off, 64);
            if (ln == 0) s_red[wv] = fr;
            __syncthreads();
            if (t == 0) {
                float fsum = 0.f;
                for (int k = 0; k < 8; ++k) fsum += s_red[k];
                float loglam = (2.f * s_scal[3] + logf(fsum)) * (1.f / 1024.f);
                float gamma = expf(-loglam);
                s_scal[0] = gamma;
                s_scal[1] = 0.5f * s_scal[2] * gamma;
            }
            __syncthreads();
        }
    }

    // ---------------- Load D into registers: wave wv owns rows 8wv..8wv+7, lane owns g in [8ln,8ln+8) ----------------
    float dRr[8][8], dIr[8][8];
    #pragma unroll
    for (int k = 0; k < 8; ++k) {
        const float4* pr = (const float4*)&dre[(8 * wv + k) * 512 + 8 * ln];
        const float4* pi = (const float4*)&dim[(8 * wv + k) * 512 + 8 * ln];
        float4 x0 = pr[0], x1 = pr[1], y0 = pi[0], y1 = pi[1];
        dRr[k][0] = x0.x; dRr[k][1] = x0.y; dRr[k][2] = x0.z; dRr[k][3] = x0.w;
        dRr[k][4] = x1.x; dRr[k][5] = x1.y; dRr[k][6] = x1.z; dRr[k][7] = x1.w;
        dIr[k][0] = y0.x; dIr[k][1] = y0.y; dIr[k][2] = y0.z; dIr[k][3] = y0.w;
        dIr[k][4] = y1.x; dIr[k][5] = y1.y; dIr[k][6] = y1.z; dIr[k][7] = y1.w;
    }

    // ---------------- Phase E: 16 ISTA layers (register D, 2 barriers/layer) ----------------
    const float gamma = s_scal[0];
    const float theta = s_scal[1];
    float* out_init = out + 40960 + (size_t)bs * 8192;
    const bool b5 = (ln & 32) != 0, b4 = (ln & 16) != 0, b3 = (ln & 8) != 0;

    for (int l = 0; l < 16; ++l) {
        float4 q0 = *(const float4*)&s_res[8 * ln];
        float4 q1 = *(const float4*)&s_res[8 * ln + 4];
        float rs[8] = {q0.x, q0.y, q0.z, q0.w, q1.x, q1.y, q1.z, q1.w};
        float uR[8], uI[8];
        #pragma unroll
        for (int k = 0; k < 8; ++k) {
            float ar = 0.f, ai = 0.f;
            #pragma unroll
            for (int j = 0; j < 8; ++j) {
                ar += dRr[k][j] * rs[j];
                ai += dIr[k][j] * rs[j];
            }
            uR[k] = ar; uI[k] = ai;
        }
        // stream-splitting reduction: 8 sums over 64 lanes
        float sR4[4], sI4[4];
        #pragma unroll
        for (int k = 0; k < 4; ++k) {
            float sendR = b5 ? uR[k] : uR[k + 4];
            float sendI = b5 ? uI[k] : uI[k + 4];
            float keepR = b5 ? uR[k + 4] : uR[k];
            float keepI = b5 ? uI[k + 4] : uI[k];
            sR4[k] = keepR + __shfl_xor(sendR, 32, 64);
            sI4[k] = keepI + __shfl_xor(sendI, 32, 64);
        }
        float tR2[2], tI2[2];
        #pragma unroll
        for (int k = 0; k < 2; ++k) {
            float sendR = b4 ? sR4[k] : sR4[k + 2];
            float sendI = b4 ? sI4[k] : sI4[k + 2];
            float keepR = b4 ? sR4[k + 2] : sR4[k];
            float keepI = b4 ? sI4[k + 2] : sI4[k];
            tR2[k] = keepR + __shfl_xor(sendR, 16, 64);
            tI2[k] = keepI + __shfl_xor(sendI, 16, 64);
        }
        float fR = (b3 ? tR2[1] : tR2[0]) + __shfl_xor(b3 ? tR2[0] : tR2[1], 8, 64);
        float fI = (b3 ? tI2[1] : tI2[0]) + __shfl_xor(b3 ? tI2[0] : tI2[1], 8, 64);
        fR += __shfl_xor(fR, 4, 64); fI += __shfl_xor(fI, 4, 64);
        fR += __shfl_xor(fR, 2, 64); fI += __shfl_xor(fI, 2, 64);
        fR += __shfl_xor(fR, 1, 64); fI += __shfl_xor(fI, 1, 64);
        float ubR[8], ubI[8];
        #pragma unroll
        for (int m = 0; m < 8; ++m) {
            ubR[m] = __shfl(fR, 8 * m, 64);
            ubI[m] = __shfl(fI, 8 * m, 64);
        }
        // w-partials over own wave's rows, own g-slice
        float pwR[8], pwI[8];
        #pragma unroll
        for (int j = 0; j < 8; ++j) {
            float wr = 0.f, wi = 0.f;
            #pragma unroll
            for (int k = 0; k < 8; ++k) {
                wr += dRr[k][j] * ubR[k] + dIr[k][j] * ubI[k];
                wi += dRr[k][j] * ubI[k] - dIr[k][j] * ubR[k];
            }
            pwR[j] = wr; pwI[j] = wi;
        }
        // stash partials: layout [j][wave][lane] -> conflict-light float2 ops
        #pragma unroll
        for (int j = 0; j < 8; ++j)
            *(float2*)&sP[j * PJ + wv * 130 + 2 * ln] = make_float2(pwR[j], pwI[j]);
        __syncthreads();
        // final: t = g = 8*(t>>3) + (t&7): sum 8 wave partials
        float wR = 0.f, wI = 0.f;
        {
            const float* pp = &sP[(t & 7) * PJ + 2 * (t >> 3)];
            #pragma unroll
            for (int w8 = 0; w8 < 8; ++w8) {
                float2 c = *(const float2*)(pp + w8 * 130);
                wR += c.x; wI += c.y;
            }
        }
        float sre = res_g + gamma * (dhr_re - wR);
        float sim = gamma * (dhr_im - wI);
        float mag = sqrtf(sre * sre + sim * sim);
        res_g = fmaxf(mag - theta, 0.f);
        out_init[l * 512 + t] = res_g;
        s_res[t] = res_g;
        __syncthreads();
    }

    // ---------------- Phase F: epilogue ----------------
    {
        float mn = res_g, mx = res_g;
        for (int off = 32; off; off >>= 1) {
            mn = fminf(mn, __shfl_down(mn, off, 64));
            mx = fmaxf(mx, __shfl_down(mx, off, 64));
        }
        if (ln == 0) { s_red[wv] = mn; s_red[8 + wv] = mx; }
        __syncthreads();
        if (t == 0) {
            float a = s_red[0], b2 = s_red[8];
            for (int k = 1; k < 8; ++k) { a = fminf(a, s_red[k]); b2 = fmaxf(b2, s_red[8 + k]); }
            s_scal[5] = a; s_scal[6] = b2;
        }
        __syncthreads();
        out[bs * 512 + t] = (res_g - s_scal[5]) / (s_scal[6] - s_scal[5] + EPS_F);
        ws[bs * 512 + t] = res_g;
    }
}

__global__ __launch_bounds__(512) void ista_ave_kernel(
    const float* __restrict__ ws, float* __restrict__ out)
{
    const int b = blockIdx.x;    // 0..7
    const int g = threadIdx.x;   // 0..511
    __shared__ float s_red[16];
    __shared__ float s_scal[2];
    float acc = 0.f;
    #pragma unroll
    for (int s = 0; s < 9; ++s) acc += ws[(b * 9 + s) * 512 + g];
    acc *= (1.f / 9.f);
    float mn = acc, mx = acc;
    for (int off = 32; off; off >>= 1) {
        mn = fminf(mn, __shfl_down(mn, off, 64));
        mx = fmaxf(mx, __shfl_down(mx, off, 64));
    }
    if ((g & 63) == 0) { s_red[g >> 6] = mn; s_red[8 + (g >> 6)] = mx; }
    __syncthreads();
    if (g == 0) {
        float a = s_red[0], b2 = s_red[8];
        for (int k = 1; k < 8; ++k) { a = fminf(a, s_red[k]); b2 = fmaxf(b2, s_red[8 + k]); }
        s_scal[0] = a; s_scal[1] = b2;
    }
    __syncthreads();
    out[36864 + b * 512 + g] = (acc - s_scal[0]) / (s_scal[1] - s_scal[0] + EPS_F);
}

extern "C" void kernel_launch(void* const* d_in, const int* in_sizes, int n_in,
                              void* d_out, int out_size, void* d_ws, size_t ws_size,
                              hipStream_t stream) {
    const float* Dre = (const float*)d_in[0];
    const float* Dim = (const float*)d_in[1];
    const float* Cre = (const float*)d_in[2];
    const float* Cim = (const float*)d_in[3];
    float* out = (float*)d_out;
    float* ws  = (float*)d_ws;

    ista_main_kernel<<<72, 512, 0, stream>>>(Dre, Dim, Cre, Cim, out, ws);
    ista_ave_kernel<<<8, 512, 0, stream>>>(ws, out);
}

// Round 4
// 291.478 us; speedup vs baseline: 1.9220x; 1.6254x over previous
//
#include <hip/hip_runtime.h>
#include <math.h>

#define N_SQ   7          // 7 squarings -> A^128; Frobenius -> trace(A^256)
#define INV_P  (1.0f / 256.0f)
#define EPS_F  1e-20f
#define PT     132        // sT pitch (floats)
#define PB     132        // sB pitch (floats)
#define PJ     1040       // sP per-j slab (floats): 8 waves * 130

typedef _Float16 h2 __attribute__((ext_vector_type(2)));

__device__ inline float cdot2(h2 a, h2 b, float c) {
#if __has_builtin(__builtin_amdgcn_fdot2)
    return __builtin_amdgcn_fdot2(a, b, c, false);
#else
    return c + (float)a.x * (float)b.x + (float)a.y * (float)b.y;
#endif
}

// ws: raw res_final per (b,s): ws[bs*512 + g], 72*512 floats.

__global__ __launch_bounds__(512, 1) void ista_main_kernel(
    const float* __restrict__ Dre, const float* __restrict__ Dim,
    const float* __restrict__ Cre, const float* __restrict__ Cim,
    float* __restrict__ out, float* __restrict__ ws)
{
    const int bs = blockIdx.x;     // 0..71
    const int t  = threadIdx.x;    // 0..511
    const int wv = t >> 6;         // wave 0..7
    const int ln = t & 63;         // lane
    const float* __restrict__ dre = Dre + (size_t)bs * 32768;
    const float* __restrict__ dim = Dim + (size_t)bs * 32768;

    __shared__ __align__(16) float sBuf[8448];   // sB (phases C/D) aliased as sP (phase E)
    __shared__ __align__(16) float sT[32 * PT];
    __shared__ __align__(16) float s_res[512];
    __shared__ __align__(16) float s_r[128];
    __shared__ float s_red[16];
    __shared__ float s_scal[8];  // 0=gamma 1=theta 2=max|Dhr| 3=E 4=1/c 5=lo 6=hi 7=norm2

    float* sB = sBuf;
    float* sP = sBuf;

    // ---------------- Phase A: r = vec(C^T) ----------------
    if (t < 64) {
        int i = t >> 3, j = t & 7;
        s_r[2 * t]     = Cre[bs * 64 + j * 8 + i];
        s_r[2 * t + 1] = Cim[bs * 64 + j * 8 + i];
    }
    __syncthreads();

    // ---------------- Phase B: Dhr[g] = sum_m conj(D[m,g]) r[m]  (t = g, coalesced) ----------------
    float dhr_re = 0.f, dhr_im = 0.f;
    #pragma unroll 8
    for (int m = 0; m < 64; ++m) {
        float ar = dre[m * 512 + t], ai = dim[m * 512 + t];
        float rr = s_r[2 * m], ri = s_r[2 * m + 1];
        dhr_re += ar * rr + ai * ri;
        dhr_im += ar * ri - ai * rr;
    }
    {
        float sv = dhr_re * dhr_re;
        float mv = sqrtf(dhr_re * dhr_re + dhr_im * dhr_im);
        for (int off = 32; off; off >>= 1) {
            sv += __shfl_down(sv, off, 64);
            mv = fmaxf(mv, __shfl_down(mv, off, 64));
        }
        if (ln == 0) { s_red[wv] = sv; s_red[8 + wv] = mv; }
        __syncthreads();
        if (t == 0) {
            float ss = 0.f, mm = 0.f;
            for (int k = 0; k < 8; ++k) { ss += s_red[k]; mm = fmaxf(mm, s_red[8 + k]); }
            s_scal[7] = ss; s_scal[2] = mm; s_scal[3] = 0.f;
        }
        __syncthreads();
    }
    float res_g = dhr_re / (sqrtf(s_scal[7]) + EPS_F);
    s_res[t] = res_g;

    // ---------------- Phase C: Gram A = D * D^H (64x64), 2x4 tiles on 512 threads ----------------
    const int ti = t >> 4;        // 0..31
    const int tj = t & 15;        // 0..15
    float accR[2][4] = {{0.f}}, accI[2][4] = {{0.f}};

    for (int gc = 0; gc < 512; gc += 32) {
        __syncthreads();
        {
            int gl = t & 31, row0 = t >> 5;
            #pragma unroll
            for (int s = 0; s < 4; ++s) {
                int row = row0 + 16 * s;
                *(float2*)&sT[gl * PT + 2 * row] =
                    make_float2(dre[row * 512 + gc + gl], dim[row * 512 + gc + gl]);
            }
        }
        __syncthreads();
        #pragma unroll 4
        for (int gg = 0; gg < 32; ++gg) {
            const float* rp = &sT[gg * PT];
            float4 a  = *(const float4*)(rp + 4 * ti);
            float4 b0 = *(const float4*)(rp + 8 * tj);
            float4 b1 = *(const float4*)(rp + 8 * tj + 4);
            float aR[2] = {a.x, a.z}, aI[2] = {a.y, a.w};
            float bR[4] = {b0.x, b0.z, b1.x, b1.z}, bI[4] = {b0.y, b0.w, b1.y, b1.w};
            #pragma unroll
            for (int p = 0; p < 2; ++p)
                #pragma unroll
                for (int q = 0; q < 4; ++q) {
                    accR[p][q] += aR[p] * bR[q] + aI[p] * bI[q];
                    accI[p][q] += aI[p] * bR[q] - aR[p] * bI[q];
                }
        }
    }
    #pragma unroll
    for (int p = 0; p < 2; ++p) {
        *(float4*)&sB[(2 * ti + p) * PB + 8 * tj] =
            make_float4(accR[p][0], accI[p][0], accR[p][1], accI[p][1]);
        *(float4*)&sB[(2 * ti + p) * PB + 8 * tj + 4] =
            make_float4(accR[p][2], accI[p][2], accR[p][3], accI[p][3]);
    }
    __syncthreads();

    // ---------------- Phase D: lambda_max via scaled squaring ----------------
    if (t < 64) {
        float dv = sB[t * PB + 2 * t];
        for (int off = 32; off; off >>= 1) dv = fmaxf(dv, __shfl_down(dv, off, 64));
        if (t == 0) { s_scal[3] = logf(dv); s_scal[4] = 1.f / dv; }
    }
    __syncthreads();
    {
        float inv = s_scal[4];
        #pragma unroll
        for (int p = 0; p < 2; ++p)
            #pragma unroll
            for (int q = 0; q < 4; ++q) {
                sB[(2 * ti + p) * PB + 8 * tj + 2 * q]     *= inv;
                sB[(2 * ti + p) * PB + 8 * tj + 2 * q + 1] *= inv;
            }
    }
    __syncthreads();

    for (int sq = 0; sq < N_SQ; ++sq) {
        float bRr[2][4] = {{0.f}}, bIr[2][4] = {{0.f}};
        #pragma unroll 4
        for (int n = 0; n < 64; ++n) {
            const float* rp = &sB[n * PB];
            float4 a  = *(const float4*)(rp + 4 * ti);
            float4 b0 = *(const float4*)(rp + 8 * tj);
            float4 b1 = *(const float4*)(rp + 8 * tj + 4);
            float aR[2] = {a.x, a.z}, aI[2] = {a.y, a.w};
            float bR[4] = {b0.x, b0.z, b1.x, b1.z}, bI[4] = {b0.y, b0.w, b1.y, b1.w};
            #pragma unroll
            for (int p = 0; p < 2; ++p)
                #pragma unroll
                for (int q = 0; q < 4; ++q) {
                    bRr[p][q] += aR[p] * bR[q] + aI[p] * bI[q];
                    bIr[p][q] += aR[p] * bI[q] - aI[p] * bR[q];
                }
        }
        float dv = 0.f;
        #pragma unroll
        for (int p = 0; p < 2; ++p)
            #pragma unroll
            for (int q = 0; q < 4; ++q)
                if (2 * ti + p == 4 * tj + q) dv = fmaxf(dv, fabsf(bRr[p][q]));
        for (int off = 32; off; off >>= 1) dv = fmaxf(dv, __shfl_down(dv, off, 64));
        if (ln == 0) s_red[wv] = dv;
        __syncthreads();
        if (t == 0) {
            float m = 0.f;
            for (int k = 0; k < 8; ++k) m = fmaxf(m, s_red[k]);
            s_scal[3] = 2.f * s_scal[3] + logf(m);
            s_scal[4] = 1.f / m;
        }
        __syncthreads();
        float ic = s_scal[4];
        if (sq < N_SQ - 1) {
            #pragma unroll
            for (int p = 0; p < 2; ++p) {
                *(float4*)&sB[(2 * ti + p) * PB + 8 * tj] =
                    make_float4(bRr[p][0] * ic, bIr[p][0] * ic, bRr[p][1] * ic, bIr[p][1] * ic);
                *(float4*)&sB[(2 * ti + p) * PB + 8 * tj + 4] =
                    make_float4(bRr[p][2] * ic, bIr[p][2] * ic, bRr[p][3] * ic, bIr[p][3] * ic);
            }
            __syncthreads();
        } else {
            float fr = 0.f;
            #pragma unroll
            for (int p = 0; p < 2; ++p)
                #pragma unroll
                for (int q = 0; q < 4; ++q)
                    fr += bRr[p][q] * bRr[p][q] + bIr[p][q] * bIr[p][q];
            fr *= ic * ic;
            for (int off = 32; off; off >>= 1) fr += __shfl_down(fr, off, 64);
            if (ln == 0) s_red[wv] = fr;
            __syncthreads();
            if (t == 0) {
                float fsum = 0.f;
                for (int k = 0; k < 8; ++k) fsum += s_red[k];
                float loglam = (2.f * s_scal[3] + logf(fsum)) * INV_P;
                float gamma = expf(-loglam);
                s_scal[0] = gamma;
                s_scal[1] = 0.5f * s_scal[2] * gamma;
            }
            __syncthreads();
        }
    }

    // ---------------- Load D tile as packed f16: wave wv owns rows 8wv..8wv+7, lane owns g in [8ln,8ln+8) ----------------
    h2 dP[8][8];   // 64 VGPRs
    #pragma unroll
    for (int k = 0; k < 8; ++k) {
        const float4* pr = (const float4*)&dre[(8 * wv + k) * 512 + 8 * ln];
        const float4* pi = (const float4*)&dim[(8 * wv + k) * 512 + 8 * ln];
        float4 x0 = pr[0], x1 = pr[1], y0 = pi[0], y1 = pi[1];
        dP[k][0] = h2{(_Float16)x0.x, (_Float16)y0.x};
        dP[k][1] = h2{(_Float16)x0.y, (_Float16)y0.y};
        dP[k][2] = h2{(_Float16)x0.z, (_Float16)y0.z};
        dP[k][3] = h2{(_Float16)x0.w, (_Float16)y0.w};
        dP[k][4] = h2{(_Float16)x1.x, (_Float16)y1.x};
        dP[k][5] = h2{(_Float16)x1.y, (_Float16)y1.y};
        dP[k][6] = h2{(_Float16)x1.z, (_Float16)y1.z};
        dP[k][7] = h2{(_Float16)x1.w, (_Float16)y1.w};
    }

    // ---------------- Phase E: 16 ISTA layers (f16 dot2, 2 barriers/layer) ----------------
    const float gamma = s_scal[0];
    const float theta = s_scal[1];
    float* out_init = out + 40960 + (size_t)bs * 8192;
    const bool b5 = (ln & 32) != 0, b4 = (ln & 16) != 0, b3 = (ln & 8) != 0;

    for (int l = 0; l < 16; ++l) {
        float4 q0 = *(const float4*)&s_res[8 * ln];
        float4 q1 = *(const float4*)&s_res[8 * ln + 4];
        float rsv[8] = {q0.x, q0.y, q0.z, q0.w, q1.x, q1.y, q1.z, q1.w};
        float uR[8] = {0.f}, uI[8] = {0.f};
        #pragma unroll
        for (int j = 0; j < 8; ++j) {
            _Float16 rh = (_Float16)rsv[j];
            h2 hA = h2{rh, (_Float16)0.f};
            h2 hB = h2{(_Float16)0.f, rh};
            #pragma unroll
            for (int k = 0; k < 8; ++k) {
                uR[k] = cdot2(dP[k][j], hA, uR[k]);
                uI[k] = cdot2(dP[k][j], hB, uI[k]);
            }
        }
        // stream-splitting reduction: 8 complex sums over 64 lanes
        float sR4[4], sI4[4];
        #pragma unroll
        for (int k = 0; k < 4; ++k) {
            float sendR = b5 ? uR[k] : uR[k + 4];
            float sendI = b5 ? uI[k] : uI[k + 4];
            float keepR = b5 ? uR[k + 4] : uR[k];
            float keepI = b5 ? uI[k + 4] : uI[k];
            sR4[k] = keepR + __shfl_xor(sendR, 32, 64);
            sI4[k] = keepI + __shfl_xor(sendI, 32, 64);
        }
        float tR2[2], tI2[2];
        #pragma unroll
        for (int k = 0; k < 2; ++k) {
            float sendR = b4 ? sR4[k] : sR4[k + 2];
            float sendI = b4 ? sI4[k] : sI4[k + 2];
            float keepR = b4 ? sR4[k + 2] : sR4[k];
            float keepI = b4 ? sI4[k + 2] : sI4[k];
            tR2[k] = keepR + __shfl_xor(sendR, 16, 64);
            tI2[k] = keepI + __shfl_xor(sendI, 16, 64);
        }
        float fR = (b3 ? tR2[1] : tR2[0]) + __shfl_xor(b3 ? tR2[0] : tR2[1], 8, 64);
        float fI = (b3 ? tI2[1] : tI2[0]) + __shfl_xor(b3 ? tI2[0] : tI2[1], 8, 64);
        fR += __shfl_xor(fR, 4, 64); fI += __shfl_xor(fI, 4, 64);
        fR += __shfl_xor(fR, 2, 64); fI += __shfl_xor(fI, 2, 64);
        fR += __shfl_xor(fR, 1, 64); fI += __shfl_xor(fI, 1, 64);
        // broadcast + pack u as f16 pairs (hu1=(re,im), hu2=(im,-re))
        h2 hu1[8], hu2[8];
        #pragma unroll
        for (int m = 0; m < 8; ++m) {
            float br = __shfl(fR, 8 * m, 64);
            float bi = __shfl(fI, 8 * m, 64);
            hu1[m] = h2{(_Float16)br, (_Float16)bi};
            hu2[m] = h2{(_Float16)bi, (_Float16)(-br)};
        }
        // w-partials: for g = 8ln+j over this wave's 8 rows; stash float2 in LDS
        #pragma unroll
        for (int j = 0; j < 8; ++j) {
            float wr = 0.f, wi = 0.f;
            #pragma unroll
            for (int k = 0; k < 8; ++k) {
                wr = cdot2(dP[k][j], hu1[k], wr);
                wi = cdot2(dP[k][j], hu2[k], wi);
            }
            *(float2*)&sP[j * PJ + wv * 130 + 2 * ln] = make_float2(wr, wi);
        }
        __syncthreads();
        float wR = 0.f, wI = 0.f;
        {
            const float* pp = &sP[(t & 7) * PJ + 2 * (t >> 3)];
            #pragma unroll
            for (int w8 = 0; w8 < 8; ++w8) {
                float2 c = *(const float2*)(pp + w8 * 130);
                wR += c.x; wI += c.y;
            }
        }
        float sre = res_g + gamma * (dhr_re - wR);
        float sim = gamma * (dhr_im - wI);
        float mag = sqrtf(sre * sre + sim * sim);
        res_g = fmaxf(mag - theta, 0.f);
        out_init[l * 512 + t] = res_g;
        s_res[t] = res_g;
        __syncthreads();
    }

    // ---------------- Phase F: epilogue ----------------
    {
        float mn = res_g, mx = res_g;
        for (int off = 32; off; off >>= 1) {
            mn = fminf(mn, __shfl_down(mn, off, 64));
            mx = fmaxf(mx, __shfl_down(mx, off, 64));
        }
        if (ln == 0) { s_red[wv] = mn; s_red[8 + wv] = mx; }
        __syncthreads();
        if (t == 0) {
            float a = s_red[0], b2 = s_red[8];
            for (int k = 1; k < 8; ++k) { a = fminf(a, s_red[k]); b2 = fmaxf(b2, s_red[8 + k]); }
            s_scal[5] = a; s_scal[6] = b2;
        }
        __syncthreads();
        out[bs * 512 + t] = (res_g - s_scal[5]) / (s_scal[6] - s_scal[5] + EPS_F);
        ws[bs * 512 + t] = res_g;
    }
}

__global__ __launch_bounds__(512) void ista_ave_kernel(
    const float* __restrict__ ws, float* __restrict__ out)
{
    const int b = blockIdx.x;    // 0..7
    const int g = threadIdx.x;   // 0..511
    __shared__ float s_red[16];
    __shared__ float s_scal[2];
    float acc = 0.f;
    #pragma unroll
    for (int s = 0; s < 9; ++s) acc += ws[(b * 9 + s) * 512 + g];
    acc *= (1.f / 9.f);
    float mn = acc, mx = acc;
    for (int off = 32; off; off >>= 1) {
        mn = fminf(mn, __shfl_down(mn, off, 64));
        mx = fmaxf(mx, __shfl_down(mx, off, 64));
    }
    if ((g & 63) == 0) { s_red[g >> 6] = mn; s_red[8 + (g >> 6)] = mx; }
    __syncthreads();
    if (g == 0) {
        float a = s_red[0], b2 = s_red[8];
        for (int k = 1; k < 8; ++k) { a = fminf(a, s_red[k]); b2 = fmaxf(b2, s_red[8 + k]); }
        s_scal[0] = a; s_scal[1] = b2;
    }
    __syncthreads();
    out[36864 + b * 512 + g] = (acc - s_scal[0]) / (s_scal[1] - s_scal[0] + EPS_F);
}

extern "C" void kernel_launch(void* const* d_in, const int* in_sizes, int n_in,
                              void* d_out, int out_size, void* d_ws, size_t ws_size,
                              hipStream_t stream) {
    const float* Dre = (const float*)d_in[0];
    const float* Dim = (const float*)d_in[1];
    const float* Cre = (const float*)d_in[2];
    const float* Cim = (const float*)d_in[3];
    float* out = (float*)d_out;
    float* ws  = (float*)d_ws;

    ista_main_kernel<<<72, 512, 0, stream>>>(Dre, Dim, Cre, Cim, out, ws);
    ista_ave_kernel<<<8, 512, 0, stream>>>(ws, out);
}

// Round 5
// 134.173 us; speedup vs baseline: 4.1754x; 2.1724x over previous
//
#include <hip/hip_runtime.h>
#include <math.h>

#define N_SQ   7          // 7 squarings -> A^128; Frobenius -> trace(A^256)
#define INV_P  (1.0f / 256.0f)
#define EPS_F  1e-20f
#define PH     72         // f16 pitch for staged 64-row planes (pad kills bank conflicts)
#define PQ     67         // f32 pitch for Q1 transpose buffer
#define PJ     1040       // sP per-j slab (floats): 8 waves * 130

typedef _Float16 h2   __attribute__((ext_vector_type(2)));
typedef _Float16 f16x4 __attribute__((ext_vector_type(4)));
typedef _Float16 f16x8 __attribute__((ext_vector_type(8)));
typedef float    f32x4 __attribute__((ext_vector_type(4)));

__device__ inline float cdot2(h2 a, h2 b, float c) {
#if __has_builtin(__builtin_amdgcn_fdot2)
    return __builtin_amdgcn_fdot2(a, b, c, false);
#else
    return c + (float)a.x * (float)b.x + (float)a.y * (float)b.y;
#endif
}

// ws: raw res_final per (b,s): ws[bs*512 + g], 72*512 floats.

__global__ __launch_bounds__(512, 1) void ista_main_kernel(
    const float* __restrict__ Dre, const float* __restrict__ Dim,
    const float* __restrict__ Cre, const float* __restrict__ Cim,
    float* __restrict__ out, float* __restrict__ ws)
{
    const int bs = blockIdx.x;     // 0..71
    const int t  = threadIdx.x;    // 0..511
    const int wv = t >> 6;         // wave 0..7
    const int ln = t & 63;         // lane
    const int c16 = ln & 15;       // MFMA col / row-select
    const int qd  = ln >> 4;       // MFMA quad
    const float* __restrict__ dre = Dre + (size_t)bs * 32768;
    const float* __restrict__ dim = Dim + (size_t)bs * 32768;

    // Unified buffer: ShRe f16[64*PH] | ShIm f16[64*PH] | Q1 f32[64*PQ]; phase E aliases as sP.
    __shared__ __align__(16) float uBuf[9216];          // 36864 B
    _Float16* ShRe = (_Float16*)uBuf;                   // bytes [0, 9216)
    _Float16* ShIm = (_Float16*)uBuf + 64 * PH;         // bytes [9216, 18432)
    float*    Q1   = uBuf + 4608;                       // bytes [18432, 35584)
    float*    sP   = uBuf;                              // phase E partial stash (33280 B)
    __shared__ __align__(16) float s_res[512];
    __shared__ __align__(16) float s_r[128];
    __shared__ float s_red[16];
    __shared__ float s_scal[8];  // 0=gamma 1=theta 2=max|Dhr| 3=E(log) 4=1/c 5=lo 6=hi 7=norm2

    // ---------------- Phase A: r = vec(C^T) ----------------
    if (t < 64) {
        int i = t >> 3, j = t & 7;
        s_r[2 * t]     = Cre[bs * 64 + j * 8 + i];
        s_r[2 * t + 1] = Cim[bs * 64 + j * 8 + i];
    }
    __syncthreads();

    // ---------------- Phase B: Dhr[g] = sum_m conj(D[m,g]) r[m]  (t = g, coalesced f32) ----------------
    float dhr_re = 0.f, dhr_im = 0.f;
    #pragma unroll 8
    for (int m = 0; m < 64; ++m) {
        float ar = dre[m * 512 + t], ai = dim[m * 512 + t];
        float rr = s_r[2 * m], ri = s_r[2 * m + 1];
        dhr_re += ar * rr + ai * ri;
        dhr_im += ar * ri - ai * rr;
    }
    {
        float sv = dhr_re * dhr_re;
        float mv = sqrtf(dhr_re * dhr_re + dhr_im * dhr_im);
        for (int off = 32; off; off >>= 1) {
            sv += __shfl_down(sv, off, 64);
            mv = fmaxf(mv, __shfl_down(mv, off, 64));
        }
        if (ln == 0) { s_red[wv] = sv; s_red[8 + wv] = mv; }
        __syncthreads();
        if (t == 0) {
            float ss = 0.f, mm = 0.f;
            for (int k = 0; k < 8; ++k) { ss += s_red[k]; mm = fmaxf(mm, s_red[8 + k]); }
            s_scal[7] = ss; s_scal[2] = mm;
        }
        __syncthreads();
    }
    float res_g = dhr_re / (sqrtf(s_scal[7]) + EPS_F);
    s_res[t] = res_g;

    // ---------------- MFMA tile ownership: wave wv owns output tiles 2wv, 2wv+1 (of 4x4) ----------------
    const int tau0 = 2 * wv, tau1 = 2 * wv + 1;
    const int I0 = tau0 >> 2, J0 = tau0 & 3;
    const int I1 = tau1 >> 2, J1 = tau1 & 3;

    // Epilogue shared by Gram & squarings: given Re-acc (P) and Q1-acc per tile,
    // form Hermitian result, rescale by max|Re diag|, store f16 (or Frobenius on last).
    auto epilogue = [&](f32x4 P0, f32x4 Qa0, f32x4 P1, f32x4 Qa1, bool first, bool last) {
        #pragma unroll
        for (int r = 0; r < 4; ++r) {
            Q1[(I0 * 16 + qd * 4 + r) * PQ + J0 * 16 + c16] = Qa0[r];
            Q1[(I1 * 16 + qd * 4 + r) * PQ + J1 * 16 + c16] = Qa1[r];
        }
        float dv = 0.f;
        if (I0 == J0) {
            #pragma unroll
            for (int r = 0; r < 4; ++r) if (qd * 4 + r == c16) dv = fmaxf(dv, fabsf(P0[r]));
        }
        if (I1 == J1) {
            #pragma unroll
            for (int r = 0; r < 4; ++r) if (qd * 4 + r == c16) dv = fmaxf(dv, fabsf(P1[r]));
        }
        for (int off = 32; off; off >>= 1) dv = fmaxf(dv, __shfl_down(dv, off, 64));
        if (ln == 0) s_red[wv] = dv;
        __syncthreads();   // Q1 visible; diag partials ready; all frag reads done
        if (t == 0) {
            float m = 0.f;
            for (int k = 0; k < 8; ++k) m = fmaxf(m, s_red[k]);
            s_scal[3] = first ? logf(m) : 2.f * s_scal[3] + logf(m);
            s_scal[4] = 1.f / m;
        }
        __syncthreads();
        float ic = s_scal[4];
        float ci0[4], ci1[4];
        #pragma unroll
        for (int r = 0; r < 4; ++r) {
            ci0[r] = Qa0[r] - Q1[(J0 * 16 + c16) * PQ + I0 * 16 + qd * 4 + r];
            ci1[r] = Qa1[r] - Q1[(J1 * 16 + c16) * PQ + I1 * 16 + qd * 4 + r];
        }
        if (!last) {
            #pragma unroll
            for (int r = 0; r < 4; ++r) {
                ShRe[(I0 * 16 + qd * 4 + r) * PH + J0 * 16 + c16] = (_Float16)(P0[r] * ic);
                ShIm[(I0 * 16 + qd * 4 + r) * PH + J0 * 16 + c16] = (_Float16)(ci0[r] * ic);
                ShRe[(I1 * 16 + qd * 4 + r) * PH + J1 * 16 + c16] = (_Float16)(P1[r] * ic);
                ShIm[(I1 * 16 + qd * 4 + r) * PH + J1 * 16 + c16] = (_Float16)(ci1[r] * ic);
            }
            __syncthreads();
        } else {
            float fr = 0.f;
            #pragma unroll
            for (int r = 0; r < 4; ++r)
                fr += P0[r] * P0[r] + ci0[r] * ci0[r] + P1[r] * P1[r] + ci1[r] * ci1[r];
            fr *= ic * ic;
            for (int off = 32; off; off >>= 1) fr += __shfl_down(fr, off, 64);
            if (ln == 0) s_red[wv] = fr;
            __syncthreads();
            if (t == 0) {
                float fsum = 0.f;
                for (int k = 0; k < 8; ++k) fsum += s_red[k];
                float loglam = (2.f * s_scal[3] + logf(fsum)) * INV_P;
                float gamma = expf(-loglam);
                s_scal[0] = gamma;
                s_scal[1] = 0.5f * s_scal[2] * gamma;
            }
            __syncthreads();
        }
    };

    // ---------------- Phase C: Gram A = D * D^H via MFMA, 8 chunks of 64 g ----------------
    f32x4 gP0 = {0.f, 0.f, 0.f, 0.f}, gQ0 = {0.f, 0.f, 0.f, 0.f};
    f32x4 gP1 = {0.f, 0.f, 0.f, 0.f}, gQ1 = {0.f, 0.f, 0.f, 0.f};
    {
        const int srow = t >> 4;          // 0..31
        const int scb  = (t & 15) * 4;    // col base in chunk
        float4 pr0, pi0, pr1, pi1;
        pr0 = *(const float4*)&dre[srow * 512 + scb];
        pi0 = *(const float4*)&dim[srow * 512 + scb];
        pr1 = *(const float4*)&dre[(srow + 32) * 512 + scb];
        pi1 = *(const float4*)&dim[(srow + 32) * 512 + scb];
        for (int ch = 0; ch < 8; ++ch) {
            *(f16x4*)&ShRe[srow * PH + scb] =
                f16x4{(_Float16)pr0.x, (_Float16)pr0.y, (_Float16)pr0.z, (_Float16)pr0.w};
            *(f16x4*)&ShIm[srow * PH + scb] =
                f16x4{(_Float16)pi0.x, (_Float16)pi0.y, (_Float16)pi0.z, (_Float16)pi0.w};
            *(f16x4*)&ShRe[(srow + 32) * PH + scb] =
                f16x4{(_Float16)pr1.x, (_Float16)pr1.y, (_Float16)pr1.z, (_Float16)pr1.w};
            *(f16x4*)&ShIm[(srow + 32) * PH + scb] =
                f16x4{(_Float16)pi1.x, (_Float16)pi1.y, (_Float16)pi1.z, (_Float16)pi1.w};
            if (ch < 7) {
                int gc = (ch + 1) * 64;
                pr0 = *(const float4*)&dre[srow * 512 + gc + scb];
                pi0 = *(const float4*)&dim[srow * 512 + gc + scb];
                pr1 = *(const float4*)&dre[(srow + 32) * 512 + gc + scb];
                pi1 = *(const float4*)&dim[(srow + 32) * 512 + gc + scb];
            }
            __syncthreads();
            #pragma unroll
            for (int ks = 0; ks < 64; ks += 32) {
                f16x8 arI0 = *(const f16x8*)&ShRe[(I0 * 16 + c16) * PH + ks + qd * 8];
                f16x8 aiI0 = *(const f16x8*)&ShIm[(I0 * 16 + c16) * PH + ks + qd * 8];
                f16x8 arJ0 = *(const f16x8*)&ShRe[(J0 * 16 + c16) * PH + ks + qd * 8];
                f16x8 aiJ0 = *(const f16x8*)&ShIm[(J0 * 16 + c16) * PH + ks + qd * 8];
                gP0 = __builtin_amdgcn_mfma_f32_16x16x32_f16(arI0, arJ0, gP0, 0, 0, 0);
                gP0 = __builtin_amdgcn_mfma_f32_16x16x32_f16(aiI0, aiJ0, gP0, 0, 0, 0);
                gQ0 = __builtin_amdgcn_mfma_f32_16x16x32_f16(aiI0, arJ0, gQ0, 0, 0, 0);
                f16x8 arI1 = *(const f16x8*)&ShRe[(I1 * 16 + c16) * PH + ks + qd * 8];
                f16x8 aiI1 = *(const f16x8*)&ShIm[(I1 * 16 + c16) * PH + ks + qd * 8];
                f16x8 arJ1 = *(const f16x8*)&ShRe[(J1 * 16 + c16) * PH + ks + qd * 8];
                f16x8 aiJ1 = *(const f16x8*)&ShIm[(J1 * 16 + c16) * PH + ks + qd * 8];
                gP1 = __builtin_amdgcn_mfma_f32_16x16x32_f16(arI1, arJ1, gP1, 0, 0, 0);
                gP1 = __builtin_amdgcn_mfma_f32_16x16x32_f16(aiI1, aiJ1, gP1, 0, 0, 0);
                gQ1 = __builtin_amdgcn_mfma_f32_16x16x32_f16(aiI1, arJ1, gQ1, 0, 0, 0);
            }
            __syncthreads();   // frag reads done before next chunk's staging writes
        }
    }
    // Gram epilogue: scale by max diag, store B0 as f16 (first=true)
    epilogue(gP0, gQ0, gP1, gQ1, true, false);

    // ---------------- Phase D: 7 scaled squarings via MFMA (B Hermitian: row-reads only) ----------------
    for (int sq = 0; sq < N_SQ; ++sq) {
        f32x4 P0 = {0.f, 0.f, 0.f, 0.f}, Qa0 = {0.f, 0.f, 0.f, 0.f};
        f32x4 P1 = {0.f, 0.f, 0.f, 0.f}, Qa1 = {0.f, 0.f, 0.f, 0.f};
        #pragma unroll
        for (int ks = 0; ks < 64; ks += 32) {
            f16x8 arI0 = *(const f16x8*)&ShRe[(I0 * 16 + c16) * PH + ks + qd * 8];
            f16x8 aiI0 = *(const f16x8*)&ShIm[(I0 * 16 + c16) * PH + ks + qd * 8];
            f16x8 arJ0 = *(const f16x8*)&ShRe[(J0 * 16 + c16) * PH + ks + qd * 8];
            f16x8 aiJ0 = *(const f16x8*)&ShIm[(J0 * 16 + c16) * PH + ks + qd * 8];
            P0  = __builtin_amdgcn_mfma_f32_16x16x32_f16(arI0, arJ0, P0, 0, 0, 0);
            P0  = __builtin_amdgcn_mfma_f32_16x16x32_f16(aiI0, aiJ0, P0, 0, 0, 0);
            Qa0 = __builtin_amdgcn_mfma_f32_16x16x32_f16(aiI0, arJ0, Qa0, 0, 0, 0);
            f16x8 arI1 = *(const f16x8*)&ShRe[(I1 * 16 + c16) * PH + ks + qd * 8];
            f16x8 aiI1 = *(const f16x8*)&ShIm[(I1 * 16 + c16) * PH + ks + qd * 8];
            f16x8 arJ1 = *(const f16x8*)&ShRe[(J1 * 16 + c16) * PH + ks + qd * 8];
            f16x8 aiJ1 = *(const f16x8*)&ShIm[(J1 * 16 + c16) * PH + ks + qd * 8];
            P1  = __builtin_amdgcn_mfma_f32_16x16x32_f16(arI1, arJ1, P1, 0, 0, 0);
            P1  = __builtin_amdgcn_mfma_f32_16x16x32_f16(aiI1, aiJ1, P1, 0, 0, 0);
            Qa1 = __builtin_amdgcn_mfma_f32_16x16x32_f16(aiI1, arJ1, Qa1, 0, 0, 0);
        }
        epilogue(P0, Qa0, P1, Qa1, false, sq == N_SQ - 1);
    }

    // ---------------- Load D tile as packed f16: wave wv owns rows 8wv..8wv+7, lane owns g in [8ln,8ln+8) ----------------
    h2 dP[8][8];   // 64 VGPRs
    #pragma unroll
    for (int k = 0; k < 8; ++k) {
        const float4* pr = (const float4*)&dre[(8 * wv + k) * 512 + 8 * ln];
        const float4* pi = (const float4*)&dim[(8 * wv + k) * 512 + 8 * ln];
        float4 x0 = pr[0], x1 = pr[1], y0 = pi[0], y1 = pi[1];
        dP[k][0] = h2{(_Float16)x0.x, (_Float16)y0.x};
        dP[k][1] = h2{(_Float16)x0.y, (_Float16)y0.y};
        dP[k][2] = h2{(_Float16)x0.z, (_Float16)y0.z};
        dP[k][3] = h2{(_Float16)x0.w, (_Float16)y0.w};
        dP[k][4] = h2{(_Float16)x1.x, (_Float16)y1.x};
        dP[k][5] = h2{(_Float16)x1.y, (_Float16)y1.y};
        dP[k][6] = h2{(_Float16)x1.z, (_Float16)y1.z};
        dP[k][7] = h2{(_Float16)x1.w, (_Float16)y1.w};
    }

    // ---------------- Phase E: 16 ISTA layers (f16 dot2, 2 barriers/layer) ----------------
    const float gamma = s_scal[0];
    const float theta = s_scal[1];
    float* out_init = out + 40960 + (size_t)bs * 8192;
    const bool b5 = (ln & 32) != 0, b4 = (ln & 16) != 0, b3 = (ln & 8) != 0;

    for (int l = 0; l < 16; ++l) {
        float4 q0 = *(const float4*)&s_res[8 * ln];
        float4 q1 = *(const float4*)&s_res[8 * ln + 4];
        float rsv[8] = {q0.x, q0.y, q0.z, q0.w, q1.x, q1.y, q1.z, q1.w};
        float uR[8] = {0.f}, uI[8] = {0.f};
        #pragma unroll
        for (int j = 0; j < 8; ++j) {
            _Float16 rh = (_Float16)rsv[j];
            h2 hA = h2{rh, (_Float16)0.f};
            h2 hB = h2{(_Float16)0.f, rh};
            #pragma unroll
            for (int k = 0; k < 8; ++k) {
                uR[k] = cdot2(dP[k][j], hA, uR[k]);
                uI[k] = cdot2(dP[k][j], hB, uI[k]);
            }
        }
        // stream-splitting reduction: 8 complex sums over 64 lanes
        float sR4[4], sI4[4];
        #pragma unroll
        for (int k = 0; k < 4; ++k) {
            float sendR = b5 ? uR[k] : uR[k + 4];
            float sendI = b5 ? uI[k] : uI[k + 4];
            float keepR = b5 ? uR[k + 4] : uR[k];
            float keepI = b5 ? uI[k + 4] : uI[k];
            sR4[k] = keepR + __shfl_xor(sendR, 32, 64);
            sI4[k] = keepI + __shfl_xor(sendI, 32, 64);
        }
        float tR2[2], tI2[2];
        #pragma unroll
        for (int k = 0; k < 2; ++k) {
            float sendR = b4 ? sR4[k] : sR4[k + 2];
            float sendI = b4 ? sI4[k] : sI4[k + 2];
            float keepR = b4 ? sR4[k + 2] : sR4[k];
            float keepI = b4 ? sI4[k + 2] : sI4[k];
            tR2[k] = keepR + __shfl_xor(sendR, 16, 64);
            tI2[k] = keepI + __shfl_xor(sendI, 16, 64);
        }
        float fR = (b3 ? tR2[1] : tR2[0]) + __shfl_xor(b3 ? tR2[0] : tR2[1], 8, 64);
        float fI = (b3 ? tI2[1] : tI2[0]) + __shfl_xor(b3 ? tI2[0] : tI2[1], 8, 64);
        fR += __shfl_xor(fR, 4, 64); fI += __shfl_xor(fI, 4, 64);
        fR += __shfl_xor(fR, 2, 64); fI += __shfl_xor(fI, 2, 64);
        fR += __shfl_xor(fR, 1, 64); fI += __shfl_xor(fI, 1, 64);
        h2 hu1[8], hu2[8];
        #pragma unroll
        for (int m = 0; m < 8; ++m) {
            float br = __shfl(fR, 8 * m, 64);
            float bi = __shfl(fI, 8 * m, 64);
            hu1[m] = h2{(_Float16)br, (_Float16)bi};
            hu2[m] = h2{(_Float16)bi, (_Float16)(-br)};
        }
        #pragma unroll
        for (int j = 0; j < 8; ++j) {
            float wr = 0.f, wi = 0.f;
            #pragma unroll
            for (int k = 0; k < 8; ++k) {
                wr = cdot2(dP[k][j], hu1[k], wr);
                wi = cdot2(dP[k][j], hu2[k], wi);
            }
            *(float2*)&sP[j * PJ + wv * 130 + 2 * ln] = make_float2(wr, wi);
        }
        __syncthreads();
        float wR = 0.f, wI = 0.f;
        {
            const float* pp = &sP[(t & 7) * PJ + 2 * (t >> 3)];
            #pragma unroll
            for (int w8 = 0; w8 < 8; ++w8) {
                float2 c = *(const float2*)(pp + w8 * 130);
                wR += c.x; wI += c.y;
            }
        }
        float sre = res_g + gamma * (dhr_re - wR);
        float sim = gamma * (dhr_im - wI);
        float mag = sqrtf(sre * sre + sim * sim);
        res_g = fmaxf(mag - theta, 0.f);
        out_init[l * 512 + t] = res_g;
        s_res[t] = res_g;
        __syncthreads();
    }

    // ---------------- Phase F: epilogue ----------------
    {
        float mn = res_g, mx = res_g;
        for (int off = 32; off; off >>= 1) {
            mn = fminf(mn, __shfl_down(mn, off, 64));
            mx = fmaxf(mx, __shfl_down(mx, off, 64));
        }
        if (ln == 0) { s_red[wv] = mn; s_red[8 + wv] = mx; }
        __syncthreads();
        if (t == 0) {
            float a = s_red[0], b2 = s_red[8];
            for (int k = 1; k < 8; ++k) { a = fminf(a, s_red[k]); b2 = fmaxf(b2, s_red[8 + k]); }
            s_scal[5] = a; s_scal[6] = b2;
        }
        __syncthreads();
        out[bs * 512 + t] = (res_g - s_scal[5]) / (s_scal[6] - s_scal[5] + EPS_F);
        ws[bs * 512 + t] = res_g;
    }
}

__global__ __launch_bounds__(512) void ista_ave_kernel(
    const float* __restrict__ ws, float* __restrict__ out)
{
    const int b = blockIdx.x;    // 0..7
    const int g = threadIdx.x;   // 0..511
    __shared__ float s_red[16];
    __shared__ float s_scal[2];
    float acc = 0.f;
    #pragma unroll
    for (int s = 0; s < 9; ++s) acc += ws[(b * 9 + s) * 512 + g];
    acc *= (1.f / 9.f);
    float mn = acc, mx = acc;
    for (int off = 32; off; off >>= 1) {
        mn = fminf(mn, __shfl_down(mn, off, 64));
        mx = fmaxf(mx, __shfl_down(mx, off, 64));
    }
    if ((g & 63) == 0) { s_red[g >> 6] = mn; s_red[8 + (g >> 6)] = mx; }
    __syncthreads();
    if (g == 0) {
        float a = s_red[0], b2 = s_red[8];
        for (int k = 1; k < 8; ++k) { a = fminf(a, s_red[k]); b2 = fmaxf(b2, s_red[8 + k]); }
        s_scal[0] = a; s_scal[1] = b2;
    }
    __syncthreads();
    out[36864 + b * 512 + g] = (acc - s_scal[0]) / (s_scal[1] - s_scal[0] + EPS_F);
}

extern "C" void kernel_launch(void* const* d_in, const int* in_sizes, int n_in,
                              void* d_out, int out_size, void* d_ws, size_t ws_size,
                              hipStream_t stream) {
    const float* Dre = (const float*)d_in[0];
    const float* Dim = (const float*)d_in[1];
    const float* Cre = (const float*)d_in[2];
    const float* Cim = (const float*)d_in[3];
    float* out = (float*)d_out;
    float* ws  = (float*)d_ws;

    ista_main_kernel<<<72, 512, 0, stream>>>(Dre, Dim, Cre, Cim, out, ws);
    ista_ave_kernel<<<8, 512, 0, stream>>>(ws, out);
}

// Round 6
// 112.631 us; speedup vs baseline: 4.9739x; 1.1913x over previous
//
#include <hip/hip_runtime.h>
#include <math.h>

#define N_SQ   7          // 7 squarings -> A^128; Frobenius -> trace(A^256)
#define INV_P  (1.0f / 256.0f)
#define EPS_F  1e-20f
#define PH     72         // f16 pitch for staged 64-row planes
#define PQ     67         // f32 pitch for Q1 transpose buffer

typedef _Float16 h2    __attribute__((ext_vector_type(2)));
typedef _Float16 f16x8 __attribute__((ext_vector_type(8)));
typedef float    f32x4 __attribute__((ext_vector_type(4)));

__device__ inline float cdot2(h2 a, h2 b, float c) {
#if __has_builtin(__builtin_amdgcn_fdot2)
    return __builtin_amdgcn_fdot2(a, b, c, false);
#else
    return c + (float)a.x * (float)b.x + (float)a.y * (float)b.y;
#endif
}
__device__ inline h2 bch2(unsigned int x) { return __builtin_bit_cast(h2, x); }
__device__ inline h2 bch2f(float x)       { return __builtin_bit_cast(h2, x); }
__device__ inline float bcf(h2 x)         { return __builtin_bit_cast(float, x); }

// ws: raw res_final per (b,s): ws[bs*512 + g], 72*512 floats.

__global__ __launch_bounds__(512, 1) void ista_main_kernel(
    const float* __restrict__ Dre, const float* __restrict__ Dim,
    const float* __restrict__ Cre, const float* __restrict__ Cim,
    float* __restrict__ out, float* __restrict__ ws)
{
    const int bs = blockIdx.x;     // 0..71
    const int t  = threadIdx.x;    // 0..511
    const int wv = t >> 6;         // wave 0..7
    const int ln = t & 63;         // lane
    const int c16 = ln & 15;       // MFMA col / row-select
    const int qd  = ln >> 4;       // MFMA quad
    const float* __restrict__ dre = Dre + (size_t)bs * 32768;
    const float* __restrict__ dim = Dim + (size_t)bs * 32768;

    // Unified buffer: phases C/D: ShRe f16[64*PH] | ShIm f16[64*PH] | Q1 f32[64*PQ]
    // Phase E aliases: sUp f32[1024] | sHu f32[128] | sResH f16[512]
    __shared__ __align__(16) float uBuf[9216];          // 36864 B
    _Float16* ShRe = (_Float16*)uBuf;
    _Float16* ShIm = (_Float16*)uBuf + 64 * PH;
    float*    Q1   = uBuf + 4608;
    float*    sUp  = uBuf;                              // [0,1024) floats
    float*    sHu  = uBuf + 1024;                       // [1024,1152)
    _Float16* sResH = (_Float16*)(uBuf + 1152);         // 512 f16
    __shared__ __align__(16) float s_r[128];
    __shared__ float s_red[16];
    __shared__ float s_scal[8];  // 0=gamma 1=theta 2=max|Dhr| 3=E(log) 4=1/c 5=lo 6=hi 7=norm2

    // ---------------- Phase A: r = vec(C^T) ----------------
    if (t < 64) {
        int i = t >> 3, j = t & 7;
        s_r[2 * t]     = Cre[bs * 64 + j * 8 + i];
        s_r[2 * t + 1] = Cim[bs * 64 + j * 8 + i];
    }
    __syncthreads();

    // ---------------- Phase B: Dhr[g] + build dV column tile (same loads) ----------------
    float dhr_re = 0.f, dhr_im = 0.f;
    h2 dV[64];    // D[m][t] packed (re,im) f16
    #pragma unroll
    for (int m = 0; m < 64; ++m) {
        float ar = dre[m * 512 + t], ai = dim[m * 512 + t];
        dV[m] = h2{(_Float16)ar, (_Float16)ai};
        float rr = s_r[2 * m], ri = s_r[2 * m + 1];
        dhr_re += ar * rr + ai * ri;
        dhr_im += ar * ri - ai * rr;
    }
    {
        float sv = dhr_re * dhr_re;
        float mv = sqrtf(dhr_re * dhr_re + dhr_im * dhr_im);
        for (int off = 32; off; off >>= 1) {
            sv += __shfl_down(sv, off, 64);
            mv = fmaxf(mv, __shfl_down(mv, off, 64));
        }
        if (ln == 0) { s_red[wv] = sv; s_red[8 + wv] = mv; }
        __syncthreads();
        if (t == 0) {
            float ss = 0.f, mm = 0.f;
            for (int k = 0; k < 8; ++k) { ss += s_red[k]; mm = fmaxf(mm, s_red[8 + k]); }
            s_scal[7] = ss; s_scal[2] = mm;
        }
        __syncthreads();
    }
    float res_g = dhr_re / (sqrtf(s_scal[7]) + EPS_F);

    // ---------------- MFMA tile ownership ----------------
    const int tau0 = 2 * wv, tau1 = 2 * wv + 1;
    const int I0 = tau0 >> 2, J0 = tau0 & 3;
    const int I1 = tau1 >> 2, J1 = tau1 & 3;

    auto epilogue = [&](f32x4 P0, f32x4 Qa0, f32x4 P1, f32x4 Qa1, bool first, bool last) {
        #pragma unroll
        for (int r = 0; r < 4; ++r) {
            Q1[(I0 * 16 + qd * 4 + r) * PQ + J0 * 16 + c16] = Qa0[r];
            Q1[(I1 * 16 + qd * 4 + r) * PQ + J1 * 16 + c16] = Qa1[r];
        }
        float dv = 0.f;
        if (I0 == J0) {
            #pragma unroll
            for (int r = 0; r < 4; ++r) if (qd * 4 + r == c16) dv = fmaxf(dv, fabsf(P0[r]));
        }
        if (I1 == J1) {
            #pragma unroll
            for (int r = 0; r < 4; ++r) if (qd * 4 + r == c16) dv = fmaxf(dv, fabsf(P1[r]));
        }
        for (int off = 32; off; off >>= 1) dv = fmaxf(dv, __shfl_down(dv, off, 64));
        if (ln == 0) s_red[wv] = dv;
        __syncthreads();
        if (t == 0) {
            float m = 0.f;
            for (int k = 0; k < 8; ++k) m = fmaxf(m, s_red[k]);
            s_scal[3] = first ? logf(m) : 2.f * s_scal[3] + logf(m);
            s_scal[4] = 1.f / m;
        }
        __syncthreads();
        float ic = s_scal[4];
        float ci0[4], ci1[4];
        #pragma unroll
        for (int r = 0; r < 4; ++r) {
            ci0[r] = Qa0[r] - Q1[(J0 * 16 + c16) * PQ + I0 * 16 + qd * 4 + r];
            ci1[r] = Qa1[r] - Q1[(J1 * 16 + c16) * PQ + I1 * 16 + qd * 4 + r];
        }
        if (!last) {
            #pragma unroll
            for (int r = 0; r < 4; ++r) {
                ShRe[(I0 * 16 + qd * 4 + r) * PH + J0 * 16 + c16] = (_Float16)(P0[r] * ic);
                ShIm[(I0 * 16 + qd * 4 + r) * PH + J0 * 16 + c16] = (_Float16)(ci0[r] * ic);
                ShRe[(I1 * 16 + qd * 4 + r) * PH + J1 * 16 + c16] = (_Float16)(P1[r] * ic);
                ShIm[(I1 * 16 + qd * 4 + r) * PH + J1 * 16 + c16] = (_Float16)(ci1[r] * ic);
            }
            __syncthreads();
        } else {
            float fr = 0.f;
            #pragma unroll
            for (int r = 0; r < 4; ++r)
                fr += P0[r] * P0[r] + ci0[r] * ci0[r] + P1[r] * P1[r] + ci1[r] * ci1[r];
            fr *= ic * ic;
            for (int off = 32; off; off >>= 1) fr += __shfl_down(fr, off, 64);
            if (ln == 0) s_red[wv] = fr;
            __syncthreads();
            if (t == 0) {
                float fsum = 0.f;
                for (int k = 0; k < 8; ++k) fsum += s_red[k];
                float loglam = (2.f * s_scal[3] + logf(fsum)) * INV_P;
                float gamma = expf(-loglam);
                s_scal[0] = gamma;
                s_scal[1] = 0.5f * s_scal[2] * gamma;
            }
            __syncthreads();
        }
    };

    // ---------------- Phase C: Gram via MFMA; grab dU row tile when ch==wv ----------------
    h2 du_re[32], du_im[32];   // g-pairs of row ln, g in [64wv, 64wv+64)
    f32x4 gP0 = {0.f, 0.f, 0.f, 0.f}, gQ0 = {0.f, 0.f, 0.f, 0.f};
    f32x4 gP1 = {0.f, 0.f, 0.f, 0.f}, gQ1 = {0.f, 0.f, 0.f, 0.f};
    {
        const int srow = t >> 4;          // 0..31
        const int scb  = (t & 15) * 4;    // col base in chunk
        float4 pr0, pi0, pr1, pi1;
        pr0 = *(const float4*)&dre[srow * 512 + scb];
        pi0 = *(const float4*)&dim[srow * 512 + scb];
        pr1 = *(const float4*)&dre[(srow + 32) * 512 + scb];
        pi1 = *(const float4*)&dim[(srow + 32) * 512 + scb];
        for (int ch = 0; ch < 8; ++ch) {
            *(h2*)&ShRe[srow * PH + scb]     = h2{(_Float16)pr0.x, (_Float16)pr0.y};
            *(h2*)&ShRe[srow * PH + scb + 2] = h2{(_Float16)pr0.z, (_Float16)pr0.w};
            *(h2*)&ShIm[srow * PH + scb]     = h2{(_Float16)pi0.x, (_Float16)pi0.y};
            *(h2*)&ShIm[srow * PH + scb + 2] = h2{(_Float16)pi0.z, (_Float16)pi0.w};
            *(h2*)&ShRe[(srow + 32) * PH + scb]     = h2{(_Float16)pr1.x, (_Float16)pr1.y};
            *(h2*)&ShRe[(srow + 32) * PH + scb + 2] = h2{(_Float16)pr1.z, (_Float16)pr1.w};
            *(h2*)&ShIm[(srow + 32) * PH + scb]     = h2{(_Float16)pi1.x, (_Float16)pi1.y};
            *(h2*)&ShIm[(srow + 32) * PH + scb + 2] = h2{(_Float16)pi1.z, (_Float16)pi1.w};
            if (ch < 7) {
                int gc = (ch + 1) * 64;
                pr0 = *(const float4*)&dre[srow * 512 + gc + scb];
                pi0 = *(const float4*)&dim[srow * 512 + gc + scb];
                pr1 = *(const float4*)&dre[(srow + 32) * 512 + gc + scb];
                pi1 = *(const float4*)&dim[(srow + 32) * 512 + gc + scb];
            }
            __syncthreads();
            #pragma unroll
            for (int ks = 0; ks < 64; ks += 32) {
                f16x8 arI0 = *(const f16x8*)&ShRe[(I0 * 16 + c16) * PH + ks + qd * 8];
                f16x8 aiI0 = *(const f16x8*)&ShIm[(I0 * 16 + c16) * PH + ks + qd * 8];
                f16x8 arJ0 = *(const f16x8*)&ShRe[(J0 * 16 + c16) * PH + ks + qd * 8];
                f16x8 aiJ0 = *(const f16x8*)&ShIm[(J0 * 16 + c16) * PH + ks + qd * 8];
                gP0 = __builtin_amdgcn_mfma_f32_16x16x32_f16(arI0, arJ0, gP0, 0, 0, 0);
                gP0 = __builtin_amdgcn_mfma_f32_16x16x32_f16(aiI0, aiJ0, gP0, 0, 0, 0);
                gQ0 = __builtin_amdgcn_mfma_f32_16x16x32_f16(aiI0, arJ0, gQ0, 0, 0, 0);
                f16x8 arI1 = *(const f16x8*)&ShRe[(I1 * 16 + c16) * PH + ks + qd * 8];
                f16x8 aiI1 = *(const f16x8*)&ShIm[(I1 * 16 + c16) * PH + ks + qd * 8];
                f16x8 arJ1 = *(const f16x8*)&ShRe[(J1 * 16 + c16) * PH + ks + qd * 8];
                f16x8 aiJ1 = *(const f16x8*)&ShIm[(J1 * 16 + c16) * PH + ks + qd * 8];
                gP1 = __builtin_amdgcn_mfma_f32_16x16x32_f16(arI1, arJ1, gP1, 0, 0, 0);
                gP1 = __builtin_amdgcn_mfma_f32_16x16x32_f16(aiI1, aiJ1, gP1, 0, 0, 0);
                gQ1 = __builtin_amdgcn_mfma_f32_16x16x32_f16(aiI1, arJ1, gQ1, 0, 0, 0);
            }
            if (ch == wv) {
                #pragma unroll
                for (int c = 0; c < 8; ++c) {
                    uint4 aw = *(const uint4*)&ShRe[ln * PH + 8 * c];
                    du_re[4 * c + 0] = bch2(aw.x); du_re[4 * c + 1] = bch2(aw.y);
                    du_re[4 * c + 2] = bch2(aw.z); du_re[4 * c + 3] = bch2(aw.w);
                    uint4 bw = *(const uint4*)&ShIm[ln * PH + 8 * c];
                    du_im[4 * c + 0] = bch2(bw.x); du_im[4 * c + 1] = bch2(bw.y);
                    du_im[4 * c + 2] = bch2(bw.z); du_im[4 * c + 3] = bch2(bw.w);
                }
            }
            __syncthreads();
        }
    }
    epilogue(gP0, gQ0, gP1, gQ1, true, false);

    // ---------------- Phase D: 7 scaled squarings via MFMA ----------------
    for (int sq = 0; sq < N_SQ; ++sq) {
        f32x4 P0 = {0.f, 0.f, 0.f, 0.f}, Qa0 = {0.f, 0.f, 0.f, 0.f};
        f32x4 P1 = {0.f, 0.f, 0.f, 0.f}, Qa1 = {0.f, 0.f, 0.f, 0.f};
        #pragma unroll
        for (int ks = 0; ks < 64; ks += 32) {
            f16x8 arI0 = *(const f16x8*)&ShRe[(I0 * 16 + c16) * PH + ks + qd * 8];
            f16x8 aiI0 = *(const f16x8*)&ShIm[(I0 * 16 + c16) * PH + ks + qd * 8];
            f16x8 arJ0 = *(const f16x8*)&ShRe[(J0 * 16 + c16) * PH + ks + qd * 8];
            f16x8 aiJ0 = *(const f16x8*)&ShIm[(J0 * 16 + c16) * PH + ks + qd * 8];
            P0  = __builtin_amdgcn_mfma_f32_16x16x32_f16(arI0, arJ0, P0, 0, 0, 0);
            P0  = __builtin_amdgcn_mfma_f32_16x16x32_f16(aiI0, aiJ0, P0, 0, 0, 0);
            Qa0 = __builtin_amdgcn_mfma_f32_16x16x32_f16(aiI0, arJ0, Qa0, 0, 0, 0);
            f16x8 arI1 = *(const f16x8*)&ShRe[(I1 * 16 + c16) * PH + ks + qd * 8];
            f16x8 aiI1 = *(const f16x8*)&ShIm[(I1 * 16 + c16) * PH + ks + qd * 8];
            f16x8 arJ1 = *(const f16x8*)&ShRe[(J1 * 16 + c16) * PH + ks + qd * 8];
            f16x8 aiJ1 = *(const f16x8*)&ShIm[(J1 * 16 + c16) * PH + ks + qd * 8];
            P1  = __builtin_amdgcn_mfma_f32_16x16x32_f16(arI1, arJ1, P1, 0, 0, 0);
            P1  = __builtin_amdgcn_mfma_f32_16x16x32_f16(aiI1, aiJ1, P1, 0, 0, 0);
            Qa1 = __builtin_amdgcn_mfma_f32_16x16x32_f16(aiI1, arJ1, Qa1, 0, 0, 0);
        }
        epilogue(P0, Qa0, P1, Qa1, false, sq == N_SQ - 1);
    }

    // ---------------- Phase E: 16 ISTA layers, shuffle-free ----------------
    const float gamma = s_scal[0];
    const float theta = s_scal[1];
    float* out_init = out + 40960 + (size_t)bs * 8192;
    const int resh_base = 64 * wv;

    for (int l = 0; l < 16; ++l) {
        sResH[t] = (_Float16)res_g;          // read back only by own wave
        float upR = 0.f, upI = 0.f;
        #pragma unroll
        for (int c = 0; c < 8; ++c) {
            uint4 rw = *(const uint4*)&sResH[resh_base + 8 * c];
            h2 r0 = bch2(rw.x), r1 = bch2(rw.y), r2 = bch2(rw.z), r3 = bch2(rw.w);
            upR = cdot2(du_re[4 * c + 0], r0, upR);  upI = cdot2(du_im[4 * c + 0], r0, upI);
            upR = cdot2(du_re[4 * c + 1], r1, upR);  upI = cdot2(du_im[4 * c + 1], r1, upI);
            upR = cdot2(du_re[4 * c + 2], r2, upR);  upI = cdot2(du_im[4 * c + 2], r2, upI);
            upR = cdot2(du_re[4 * c + 3], r3, upR);  upI = cdot2(du_im[4 * c + 3], r3, upI);
        }
        *(float2*)&sUp[(wv * 64 + ln) * 2] = make_float2(upR, upI);
        __syncthreads();
        if (wv == 0) {
            float ufR = 0.f, ufI = 0.f;
            #pragma unroll
            for (int w8 = 0; w8 < 8; ++w8) {
                float2 p = *(const float2*)&sUp[(w8 * 64 + ln) * 2];
                ufR += p.x; ufI += p.y;
            }
            h2 hu1 = h2{(_Float16)ufR, (_Float16)ufI};
            h2 hu2 = h2{(_Float16)ufI, (_Float16)(-ufR)};
            *(float2*)&sHu[2 * ln] = make_float2(bcf(hu1), bcf(hu2));
        }
        __syncthreads();
        float wR = 0.f, wI = 0.f;
        #pragma unroll
        for (int mm = 0; mm < 32; ++mm) {
            float4 hq = *(const float4*)&sHu[4 * mm];
            wR = cdot2(dV[2 * mm],     bch2f(hq.x), wR);
            wI = cdot2(dV[2 * mm],     bch2f(hq.y), wI);
            wR = cdot2(dV[2 * mm + 1], bch2f(hq.z), wR);
            wI = cdot2(dV[2 * mm + 1], bch2f(hq.w), wI);
        }
        float sre = res_g + gamma * (dhr_re - wR);
        float sim = gamma * (dhr_im - wI);
        float mag = sqrtf(sre * sre + sim * sim);
        res_g = fmaxf(mag - theta, 0.f);
        out_init[l * 512 + t] = res_g;
    }

    // ---------------- Phase F: epilogue ----------------
    {
        float mn = res_g, mx = res_g;
        for (int off = 32; off; off >>= 1) {
            mn = fminf(mn, __shfl_down(mn, off, 64));
            mx = fmaxf(mx, __shfl_down(mx, off, 64));
        }
        if (ln == 0) { s_red[wv] = mn; s_red[8 + wv] = mx; }
        __syncthreads();
        if (t == 0) {
            float a = s_red[0], b2 = s_red[8];
            for (int k = 1; k < 8; ++k) { a = fminf(a, s_red[k]); b2 = fmaxf(b2, s_red[8 + k]); }
            s_scal[5] = a; s_scal[6] = b2;
        }
        __syncthreads();
        out[bs * 512 + t] = (res_g - s_scal[5]) / (s_scal[6] - s_scal[5] + EPS_F);
        ws[bs * 512 + t] = res_g;
    }
}

__global__ __launch_bounds__(512) void ista_ave_kernel(
    const float* __restrict__ ws, float* __restrict__ out)
{
    const int b = blockIdx.x;    // 0..7
    const int g = threadIdx.x;   // 0..511
    __shared__ float s_red[16];
    __shared__ float s_scal[2];
    float acc = 0.f;
    #pragma unroll
    for (int s = 0; s < 9; ++s) acc += ws[(b * 9 + s) * 512 + g];
    acc *= (1.f / 9.f);
    float mn = acc, mx = acc;
    for (int off = 32; off; off >>= 1) {
        mn = fminf(mn, __shfl_down(mn, off, 64));
        mx = fmaxf(mx, __shfl_down(mx, off, 64));
    }
    if ((g & 63) == 0) { s_red[g >> 6] = mn; s_red[8 + (g >> 6)] = mx; }
    __syncthreads();
    if (g == 0) {
        float a = s_red[0], b2 = s_red[8];
        for (int k = 1; k < 8; ++k) { a = fminf(a, s_red[k]); b2 = fmaxf(b2, s_red[8 + k]); }
        s_scal[0] = a; s_scal[1] = b2;
    }
    __syncthreads();
    out[36864 + b * 512 + g] = (acc - s_scal[0]) / (s_scal[1] - s_scal[0] + EPS_F);
}

extern "C" void kernel_launch(void* const* d_in, const int* in_sizes, int n_in,
                              void* d_out, int out_size, void* d_ws, size_t ws_size,
                              hipStream_t stream) {
    const float* Dre = (const float*)d_in[0];
    const float* Dim = (const float*)d_in[1];
    const float* Cre = (const float*)d_in[2];
    const float* Cim = (const float*)d_in[3];
    float* out = (float*)d_out;
    float* ws  = (float*)d_ws;

    ista_main_kernel<<<72, 512, 0, stream>>>(Dre, Dim, Cre, Cim, out, ws);
    ista_ave_kernel<<<8, 512, 0, stream>>>(ws, out);
}